// Round 4
// baseline (347.659 us; speedup 1.0000x reference)
//
#include <hip/hip_runtime.h>
#include <math.h>

#define NEG_SLOPE 0.2f
#define GEPS 1e-5f
#define AGG1_BLOCKS 2048
#define AGG2_BLOCKS 2048

typedef __attribute__((ext_vector_type(8))) short short8;
typedef __attribute__((ext_vector_type(4))) float floatx4;

__device__ __forceinline__ float wave_reduce_sum(float v) {
#pragma unroll
    for (int o = 32; o > 0; o >>= 1) v += __shfl_down(v, o);
    return v;
}

__device__ __forceinline__ ushort f2bf(float f) {
    union { float f; unsigned int i; } c;
    c.f = f;
    unsigned int b = c.i;
    b += 0x7fffu + ((b >> 16) & 1u);
    return (ushort)(b >> 16);
}

__device__ __forceinline__ float bf2f(ushort u) {
    union { unsigned int i; float f; } c;
    c.i = (unsigned int)u << 16;
    return c.f;
}

__device__ __forceinline__ float2 unpack_bf2(unsigned int u) {
    union { unsigned int i; float f; } a, b;
    a.i = u << 16;            // low ushort -> even col
    b.i = u & 0xffff0000u;    // high ushort -> odd col
    return make_float2(a.f, b.f);
}

__device__ __forceinline__ unsigned int pack_bf2(float lo, float hi) {
    return (unsigned int)f2bf(lo) | ((unsigned int)f2bf(hi) << 16);
}

__device__ __forceinline__ float lrelu(float v) {
    return (v > 0.f) ? v : v * NEG_SLOPE;
}

__device__ __forceinline__ float elu_fast(float v) {
    return (v > 0.f) ? v : (__expf(v) - 1.f);
}

// ---------------- merged prologue ----------------
// blocks [0, 16)   : W2 -> bf16 MFMA B-fragment layout
// block  16        : attn consts: C1 (We1.ae1), C2 (We2.ae2), P_s1/P_d1 (W1@as1 / W1@ad1, 3/head)
// blocks [17, 273) : edge_attr column sums + degree histogram
__global__ __launch_bounds__(256) void k_pre(
    const float* __restrict__ W1, const float* __restrict__ as1, const float* __restrict__ ad1,
    const float* __restrict__ ea, const int* __restrict__ dst,
    const float* __restrict__ W2, const float* __restrict__ We1,
    const float* __restrict__ ae1, const float* __restrict__ We2,
    const float* __restrict__ ae2,
    float* __restrict__ ea_sum, int* __restrict__ deg, uint4* __restrict__ Bfrag,
    float* __restrict__ C1, float* __restrict__ C2, float* __restrict__ Ps,
    float* __restrict__ Pd, int E) {
    int b = blockIdx.x;
    if (b < 16) {
        int t = b * 256 + threadIdx.x;  // 4096 threads
        int c = t >> 9, kk = (t >> 6) & 7, L = t & 63;
        int q = L >> 4, n = c * 16 + (L & 15);
        int k0 = kk * 32 + q * 8;
        unsigned int u0 = pack_bf2(W2[(k0 + 0) * 128 + n], W2[(k0 + 1) * 128 + n]);
        unsigned int u1 = pack_bf2(W2[(k0 + 2) * 128 + n], W2[(k0 + 3) * 128 + n]);
        unsigned int u2 = pack_bf2(W2[(k0 + 4) * 128 + n], W2[(k0 + 5) * 128 + n]);
        unsigned int u3 = pack_bf2(W2[(k0 + 6) * 128 + n], W2[(k0 + 7) * 128 + n]);
        Bfrag[t] = make_uint4(u0, u1, u2, u3);
        return;
    }
    if (b == 16) {
        int t = threadIdx.x, h = t >> 6, lane = t & 63;
        float p0 = We1[t] * ae1[t];
        float p1 = We1[256 + t] * ae1[t];
        p0 = wave_reduce_sum(p0);
        p1 = wave_reduce_sum(p1);
        if (lane == 0) { C1[h] = p0; C1[4 + h] = p1; }
        float av = as1[t], dv = ad1[t];
#pragma unroll
        for (int k = 0; k < 3; ++k) {
            float wv = W1[k * 256 + t];
            float ps = wave_reduce_sum(wv * av);
            float pd = wave_reduce_sum(wv * dv);
            if (lane == 0) { Ps[h * 3 + k] = ps; Pd[h * 3 + k] = pd; }
        }
        if (t < 128) {
            float q0 = We2[t] * ae2[t];
            float q1 = We2[128 + t] * ae2[t];
            q0 = wave_reduce_sum(q0);
            q1 = wave_reduce_sum(q1);
            if (lane == 0) { C2[h] = q0; C2[2 + h] = q1; }
        }
        return;
    }
    b -= 17;
    const float2* ea2 = (const float2*)ea;
    float s0 = 0.f, s1 = 0.f;
    for (int e = b * 256 + threadIdx.x; e < E; e += 256 * 256) {
        float2 v = ea2[e];
        s0 += v.x; s1 += v.y;
        atomicAdd(&deg[dst[e]], 1);
    }
    s0 = wave_reduce_sum(s0);
    s1 = wave_reduce_sum(s1);
    if ((threadIdx.x & 63) == 0) {
        atomicAdd(&ea_sum[0], s0);
        atomicAdd(&ea_sum[1], s1);
    }
}

// ---------------- CSR row_ptr scan (block-local) ----------------
__global__ void k_scan1(const int* __restrict__ deg, int* __restrict__ row_ptr,
                        int* __restrict__ bsum, int N) {
    __shared__ int tmp[1024];
    int tid = threadIdx.x;
    int i = blockIdx.x * 1024 + tid;
    int v = (i < N) ? deg[i] : 0;
    tmp[tid] = v;
    __syncthreads();
#pragma unroll
    for (int off = 1; off < 1024; off <<= 1) {
        int t = (tid >= off) ? tmp[tid - off] : 0;
        __syncthreads();
        tmp[tid] += t;
        __syncthreads();
    }
    if (i < N) row_ptr[i + 1] = tmp[tid];
    if (tid == 1023) bsum[blockIdx.x] = tmp[1023];
}

// block prefix recomputed per block in one wave (nb1 <= 64), then applied.
// also: lE1/lE2 self-loop consts (needs ea_sum), and al_s1/al_d1 fill (x . P_s/P_d per head).
__global__ void k_scan23(int* __restrict__ row_ptr, const int* __restrict__ bsum,
                         const float* __restrict__ ea_sum, const float* __restrict__ C1,
                         const float* __restrict__ C2, const float* __restrict__ Ps,
                         const float* __restrict__ Pd, const float* __restrict__ x,
                         float* __restrict__ al_s1, float* __restrict__ al_d1,
                         float* __restrict__ lE1, float* __restrict__ lE2, int N, int E) {
    __shared__ int off_s;
    int t = threadIdx.x;
    if (blockIdx.x == 0 && t >= 64 && t < 68) {
        int k = t - 64;
        float m0 = ea_sum[0] / (float)E, m1 = ea_sum[1] / (float)E;
        lE1[k] = m0 * C1[k] + m1 * C1[4 + k];
        if (k < 2) lE2[k] = m0 * C2[k] + m1 * C2[2 + k];
    }
    if (t < 64) {
        int v = (t < blockIdx.x) ? bsum[t] : 0;
#pragma unroll
        for (int o = 32; o > 0; o >>= 1) v += __shfl_xor(v, o);
        if (t == 0) off_s = v;
    }
    __syncthreads();
    int off = off_s;
    int i = blockIdx.x * 1024 + t;
    if (i == 0) row_ptr[0] = 0;
    if (i < N) {
        row_ptr[i + 1] += off;
        float x0 = x[3 * i], x1 = x[3 * i + 1], x2 = x[3 * i + 2];
        float4 sv, dv;
        sv.x = fmaf(x0, Ps[0], fmaf(x1, Ps[1], x2 * Ps[2]));
        sv.y = fmaf(x0, Ps[3], fmaf(x1, Ps[4], x2 * Ps[5]));
        sv.z = fmaf(x0, Ps[6], fmaf(x1, Ps[7], x2 * Ps[8]));
        sv.w = fmaf(x0, Ps[9], fmaf(x1, Ps[10], x2 * Ps[11]));
        dv.x = fmaf(x0, Pd[0], fmaf(x1, Pd[1], x2 * Pd[2]));
        dv.y = fmaf(x0, Pd[3], fmaf(x1, Pd[4], x2 * Pd[5]));
        dv.z = fmaf(x0, Pd[6], fmaf(x1, Pd[7], x2 * Pd[8]));
        dv.w = fmaf(x0, Pd[9], fmaf(x1, Pd[10], x2 * Pd[11]));
        *(float4*)(al_s1 + 4 * (size_t)i) = sv;
        *(float4*)(al_d1 + 4 * (size_t)i) = dv;
    }
}

// ---------------- CSR scatter fused with layer-1 edge weights ----------------
__global__ void k_scatfill(const int* __restrict__ dst, const int* __restrict__ src,
                           const float* __restrict__ ea, const int* __restrict__ row_ptr,
                           int* __restrict__ deg, const float* __restrict__ al_s1,
                           const float* __restrict__ al_d1, const float* __restrict__ C1,
                           float4* __restrict__ ed2, uint4* __restrict__ wmp, int E) {
    int e = blockIdx.x * 256 + threadIdx.x;
    if (e >= E) return;
    int d = dst[e];
    int r = atomicSub(&deg[d], 1);
    int slot = row_ptr[d] + r - 1;
    int s = src[e];
    float2 v = ((const float2*)ea)[e];
    float4 as = *(const float4*)(al_s1 + 4 * (size_t)s);
    float4 ad = *(const float4*)(al_d1 + 4 * (size_t)d);
    float w0 = __expf(lrelu(as.x + ad.x + v.x * C1[0] + v.y * C1[4]));
    float w1 = __expf(lrelu(as.y + ad.y + v.x * C1[1] + v.y * C1[5]));
    float w2 = __expf(lrelu(as.z + ad.z + v.x * C1[2] + v.y * C1[6]));
    float w3 = __expf(lrelu(as.w + ad.w + v.x * C1[3] + v.y * C1[7]));
    ed2[slot] = make_float4(__int_as_float(s), __int_as_float(d), v.x, v.y);
    wmp[slot] = make_uint4((unsigned int)s, pack_bf2(w0, w1), pack_bf2(w2, w3), 0u);
}

// ---------------- layer-2 edge-weight fill (CSR order) ----------------
__global__ void k_fill2(const float4* __restrict__ ed2, const float* __restrict__ al_s2,
                        const float* __restrict__ al_d2, const float* __restrict__ C2,
                        float4* __restrict__ wm2, int E) {
    int e = blockIdx.x * 256 + threadIdx.x;
    if (e >= E) return;
    float4 m = ed2[e];
    int s = __float_as_int(m.x), d = __float_as_int(m.y);
    float2 as = *(const float2*)(al_s2 + 2 * (size_t)s);
    float2 ad = *(const float2*)(al_d2 + 2 * (size_t)d);
    float wA = __expf(lrelu(as.x + ad.x + m.z * C2[0] + m.w * C2[2]));
    float wB = __expf(lrelu(as.y + ad.y + m.z * C2[1] + m.w * C2[3]));
    wm2[e] = make_float4(m.x, wA, wB, 0.f);
}

// ---------------- layer-1 aggregation in x-space (linearity of W1) --------------------
// z_h = sum_e w_eh * x[src_e] (+ self), out[n] = (z_h . W1col)/dsum_h + b1. 12B gathers.
// 32 lanes per node: lane j handles edge j, 8 output cols each. Fused GraphNorm stats.
__global__ __launch_bounds__(256) void k_agg1(const float* __restrict__ x,
                                              const int* __restrict__ row_ptr,
                                              const uint4* __restrict__ wmp,
                                              const float* __restrict__ al_s,
                                              const float* __restrict__ al_d,
                                              const float* __restrict__ lE,
                                              const float* __restrict__ W1,
                                              const float* __restrict__ bias,
                                              ushort* __restrict__ out,
                                              float* __restrict__ stats, int N) {
    int l = threadIdx.x & 31;
    int grp = threadIdx.x >> 5;  // 8 node-groups per block
    int c0 = l * 8;
    int hh = l >> 3;  // head of owned columns
    // reg-resident W1 columns + bias for the 8 owned cols
    float4 wa0 = *(const float4*)(W1 + c0);
    float4 wa1 = *(const float4*)(W1 + c0 + 4);
    float4 wb0 = *(const float4*)(W1 + 256 + c0);
    float4 wb1 = *(const float4*)(W1 + 256 + c0 + 4);
    float4 wc0 = *(const float4*)(W1 + 512 + c0);
    float4 wc1 = *(const float4*)(W1 + 512 + c0 + 4);
    float4 bv0 = *(const float4*)(bias + c0);
    float4 bv1 = *(const float4*)(bias + c0 + 4);
    float le0 = lE[0], le1 = lE[1], le2 = lE[2], le3 = lE[3];
    float s8[8] = {0.f, 0.f, 0.f, 0.f, 0.f, 0.f, 0.f, 0.f};
    float q8[8] = {0.f, 0.f, 0.f, 0.f, 0.f, 0.f, 0.f, 0.f};
    for (int n = blockIdx.x * 8 + grp; n < N; n += AGG1_BLOCKS * 8) {
        float4 asn = *(const float4*)(al_s + 4 * (size_t)n);
        float4 adn = *(const float4*)(al_d + 4 * (size_t)n);
        float ws0 = __expf(lrelu(asn.x + adn.x + le0));
        float ws1 = __expf(lrelu(asn.y + adn.y + le1));
        float ws2 = __expf(lrelu(asn.z + adn.z + le2));
        float ws3 = __expf(lrelu(asn.w + adn.w + le3));
        float z[12];
        float ds[4];
#pragma unroll
        for (int k = 0; k < 12; ++k) z[k] = 0.f;
#pragma unroll
        for (int k = 0; k < 4; ++k) ds[k] = 0.f;
        int i0 = row_ptr[n];
        int cnt = row_ptr[n + 1] - i0;
        for (int j = l; j < cnt; j += 32) {
            uint4 me = wmp[i0 + j];
            int s = (int)me.x;
            float xs0 = x[3 * s], xs1 = x[3 * s + 1], xs2 = x[3 * s + 2];
            float2 w01 = unpack_bf2(me.y);
            float2 w23 = unpack_bf2(me.z);
            z[0] = fmaf(w01.x, xs0, z[0]); z[1] = fmaf(w01.x, xs1, z[1]); z[2] = fmaf(w01.x, xs2, z[2]);
            z[3] = fmaf(w01.y, xs0, z[3]); z[4] = fmaf(w01.y, xs1, z[4]); z[5] = fmaf(w01.y, xs2, z[5]);
            z[6] = fmaf(w23.x, xs0, z[6]); z[7] = fmaf(w23.x, xs1, z[7]); z[8] = fmaf(w23.x, xs2, z[8]);
            z[9] = fmaf(w23.y, xs0, z[9]); z[10] = fmaf(w23.y, xs1, z[10]); z[11] = fmaf(w23.y, xs2, z[11]);
            ds[0] += w01.x; ds[1] += w01.y; ds[2] += w23.x; ds[3] += w23.y;
        }
        // butterfly reduce 16 values across the 32-lane group
#pragma unroll
        for (int o = 16; o > 0; o >>= 1) {
#pragma unroll
            for (int k = 0; k < 12; ++k) z[k] += __shfl_xor(z[k], o);
#pragma unroll
            for (int k = 0; k < 4; ++k) ds[k] += __shfl_xor(ds[k], o);
        }
        // self-loop contribution (uniform across lanes)
        float xn0 = x[3 * n], xn1 = x[3 * n + 1], xn2 = x[3 * n + 2];
        z[0] = fmaf(ws0, xn0, z[0]); z[1] = fmaf(ws0, xn1, z[1]); z[2] = fmaf(ws0, xn2, z[2]);
        z[3] = fmaf(ws1, xn0, z[3]); z[4] = fmaf(ws1, xn1, z[4]); z[5] = fmaf(ws1, xn2, z[5]);
        z[6] = fmaf(ws2, xn0, z[6]); z[7] = fmaf(ws2, xn1, z[7]); z[8] = fmaf(ws2, xn2, z[8]);
        z[9] = fmaf(ws3, xn0, z[9]); z[10] = fmaf(ws3, xn1, z[10]); z[11] = fmaf(ws3, xn2, z[11]);
        ds[0] += ws0; ds[1] += ws1; ds[2] += ws2; ds[3] += ws3;
        // owned head's z (static selects, no dynamic reg indexing)
        float zh0 = (hh == 0) ? z[0] : (hh == 1) ? z[3] : (hh == 2) ? z[6] : z[9];
        float zh1 = (hh == 0) ? z[1] : (hh == 1) ? z[4] : (hh == 2) ? z[7] : z[10];
        float zh2 = (hh == 0) ? z[2] : (hh == 1) ? z[5] : (hh == 2) ? z[8] : z[11];
        float dsh = (hh == 0) ? ds[0] : (hh == 1) ? ds[1] : (hh == 2) ? ds[2] : ds[3];
        float inv = 1.f / dsh;
        float v0 = fmaf(fmaf(zh0, wa0.x, fmaf(zh1, wb0.x, zh2 * wc0.x)), inv, bv0.x);
        float v1 = fmaf(fmaf(zh0, wa0.y, fmaf(zh1, wb0.y, zh2 * wc0.y)), inv, bv0.y);
        float v2 = fmaf(fmaf(zh0, wa0.z, fmaf(zh1, wb0.z, zh2 * wc0.z)), inv, bv0.z);
        float v3 = fmaf(fmaf(zh0, wa0.w, fmaf(zh1, wb0.w, zh2 * wc0.w)), inv, bv0.w);
        float v4 = fmaf(fmaf(zh0, wa1.x, fmaf(zh1, wb1.x, zh2 * wc1.x)), inv, bv1.x);
        float v5 = fmaf(fmaf(zh0, wa1.y, fmaf(zh1, wb1.y, zh2 * wc1.y)), inv, bv1.y);
        float v6 = fmaf(fmaf(zh0, wa1.z, fmaf(zh1, wb1.z, zh2 * wc1.z)), inv, bv1.z);
        float v7 = fmaf(fmaf(zh0, wa1.w, fmaf(zh1, wb1.w, zh2 * wc1.w)), inv, bv1.w);
        ushort u0 = f2bf(v0), u1 = f2bf(v1), u2 = f2bf(v2), u3 = f2bf(v3);
        ushort u4 = f2bf(v4), u5 = f2bf(v5), u6 = f2bf(v6), u7 = f2bf(v7);
        float r0 = bf2f(u0), r1 = bf2f(u1), r2 = bf2f(u2), r3 = bf2f(u3);
        float r4 = bf2f(u4), r5 = bf2f(u5), r6 = bf2f(u6), r7 = bf2f(u7);
        s8[0] += r0; q8[0] = fmaf(r0, r0, q8[0]);
        s8[1] += r1; q8[1] = fmaf(r1, r1, q8[1]);
        s8[2] += r2; q8[2] = fmaf(r2, r2, q8[2]);
        s8[3] += r3; q8[3] = fmaf(r3, r3, q8[3]);
        s8[4] += r4; q8[4] = fmaf(r4, r4, q8[4]);
        s8[5] += r5; q8[5] = fmaf(r5, r5, q8[5]);
        s8[6] += r6; q8[6] = fmaf(r6, r6, q8[6]);
        s8[7] += r7; q8[7] = fmaf(r7, r7, q8[7]);
        uint4 o;
        o.x = (unsigned int)u0 | ((unsigned int)u1 << 16);
        o.y = (unsigned int)u2 | ((unsigned int)u3 << 16);
        o.z = (unsigned int)u4 | ((unsigned int)u5 << 16);
        o.w = (unsigned int)u6 | ((unsigned int)u7 << 16);
        ((uint4*)out)[(size_t)n * 32 + l] = o;
    }
    // stats: col = l*8+k; reduce 8 groups via LDS, then atomics
    __shared__ float red[8 * 32 * 16];
#pragma unroll
    for (int k = 0; k < 8; ++k) {
        red[(grp * 32 + l) * 16 + k] = s8[k];
        red[(grp * 32 + l) * 16 + 8 + k] = q8[k];
    }
    __syncthreads();
    int t = threadIdx.x;
    {
        int l2 = t >> 3, k = t & 7;
        float ss = 0.f, qq = 0.f;
#pragma unroll
        for (int g = 0; g < 8; ++g) {
            ss += red[(g * 32 + l2) * 16 + k];
            qq += red[(g * 32 + l2) * 16 + 8 + k];
        }
        atomicAdd(&stats[t], ss);
        atomicAdd(&stats[256 + t], qq);
    }
}

// ---------------- layer-2 aggregation: grid-stride, 4-stage pipeline, fused stats ------
__global__ __launch_bounds__(256) void k_agg2(const ushort* __restrict__ h2,
                                              const int* __restrict__ row_ptr,
                                              const float4* __restrict__ wm,
                                              const float* __restrict__ al_s,
                                              const float* __restrict__ al_d,
                                              const float* __restrict__ lE,
                                              const float* __restrict__ bias,
                                              ushort* __restrict__ out,
                                              float* __restrict__ stats, int N) {
    int lane = threadIdx.x & 63;
    int wv = threadIdx.x >> 6;
    int g = lane >> 4, c16 = lane & 15;
    bool hi = c16 >= 8;
    const uint4* h2u4 = (const uint4*)h2;
    float le0 = lE[0], le1 = lE[1];
    const float* bp = bias + c16 * 8;
    float4 b0 = *(const float4*)bp;
    float4 b1 = *(const float4*)(bp + 4);
    float bb[8] = {b0.x, b0.y, b0.z, b0.w, b1.x, b1.y, b1.z, b1.w};
    float s8[8] = {0.f, 0.f, 0.f, 0.f, 0.f, 0.f, 0.f, 0.f};
    float q8[8] = {0.f, 0.f, 0.f, 0.f, 0.f, 0.f, 0.f, 0.f};
    for (int n = blockIdx.x * 4 + wv; n < N; n += AGG2_BLOCKS * 4) {
        float2 adn = *(const float2*)(al_d + 2 * (size_t)n);
        float2 asn = *(const float2*)(al_s + 2 * (size_t)n);
        float wsA = __expf(lrelu(asn.x + adn.x + le0));
        float wsB = __expf(lrelu(asn.y + adn.y + le1));
        uint4 hs = h2u4[(size_t)n * 16 + c16];
        float wself = (g == 0) ? (hi ? wsB : wsA) : 0.f;
        float dsum = wself;
        float acc[8];
        {
            float2 t0 = unpack_bf2(hs.x), t1 = unpack_bf2(hs.y);
            float2 t2 = unpack_bf2(hs.z), t3 = unpack_bf2(hs.w);
            acc[0] = wself * t0.x; acc[1] = wself * t0.y;
            acc[2] = wself * t1.x; acc[3] = wself * t1.y;
            acc[4] = wself * t2.x; acc[5] = wself * t2.y;
            acc[6] = wself * t3.x; acc[7] = wself * t3.y;
        }
        int i0 = row_ptr[n];
        int cnt = row_ptr[n + 1] - i0;
        if (cnt > 0) {
            int last = cnt - 1;
            int nit = (cnt + 3) >> 2;
            int j0 = g;      float mkA = 1.f; if (j0 > last) { j0 = last; mkA = 0.f; }
            int j1 = 4 + g;  float mkB = 1.f; if (j1 > last) { j1 = last; mkB = 0.f; }
            int j2 = 8 + g;  float mkC = 1.f; if (j2 > last) { j2 = last; mkC = 0.f; }
            int j3 = 12 + g; float mkD = 1.f; if (j3 > last) { j3 = last; mkD = 0.f; }
            float4 meA = wm[i0 + j0];
            float4 meB = wm[i0 + j1];
            float4 meC = wm[i0 + j2];
            float4 meD = wm[i0 + j3];
            uint4 gvA = h2u4[(size_t)__float_as_int(meA.x) * 16 + c16];
            uint4 gvB = h2u4[(size_t)__float_as_int(meB.x) * 16 + c16];
            uint4 gvC = h2u4[(size_t)__float_as_int(meC.x) * 16 + c16];
            for (int it = 0; it < nit - 1; ++it) {
                uint4 gvD = h2u4[(size_t)__float_as_int(meD.x) * 16 + c16];
                int jn = 4 * (it + 4) + g;
                float mn = 1.f;
                if (jn > last) { jn = last; mn = 0.f; }
                float4 meE = wm[i0 + jn];
                float wg = (hi ? meA.z : meA.y) * mkA;
                dsum += wg;
                float2 u;
                u = unpack_bf2(gvA.x); acc[0] = fmaf(wg, u.x, acc[0]); acc[1] = fmaf(wg, u.y, acc[1]);
                u = unpack_bf2(gvA.y); acc[2] = fmaf(wg, u.x, acc[2]); acc[3] = fmaf(wg, u.y, acc[3]);
                u = unpack_bf2(gvA.z); acc[4] = fmaf(wg, u.x, acc[4]); acc[5] = fmaf(wg, u.y, acc[5]);
                u = unpack_bf2(gvA.w); acc[6] = fmaf(wg, u.x, acc[6]); acc[7] = fmaf(wg, u.y, acc[7]);
                meA = meB; meB = meC; meC = meD; meD = meE;
                gvA = gvB; gvB = gvC; gvC = gvD;
                mkA = mkB; mkB = mkC; mkC = mkD; mkD = mn;
            }
            float wg = (hi ? meA.z : meA.y) * mkA;
            dsum += wg;
            float2 u;
            u = unpack_bf2(gvA.x); acc[0] = fmaf(wg, u.x, acc[0]); acc[1] = fmaf(wg, u.y, acc[1]);
            u = unpack_bf2(gvA.y); acc[2] = fmaf(wg, u.x, acc[2]); acc[3] = fmaf(wg, u.y, acc[3]);
            u = unpack_bf2(gvA.z); acc[4] = fmaf(wg, u.x, acc[4]); acc[5] = fmaf(wg, u.y, acc[5]);
            u = unpack_bf2(gvA.w); acc[6] = fmaf(wg, u.x, acc[6]); acc[7] = fmaf(wg, u.y, acc[7]);
        }
#pragma unroll
        for (int k = 0; k < 8; ++k) {
            acc[k] += __shfl_xor(acc[k], 16);
            acc[k] += __shfl_xor(acc[k], 32);
        }
        dsum += __shfl_xor(dsum, 16);
        dsum += __shfl_xor(dsum, 32);
        if (g == 0) {
            float inv = 1.f / dsum;
            unsigned int ow[4];
#pragma unroll
            for (int k = 0; k < 4; ++k) {
                float va = fmaf(acc[2 * k], inv, bb[2 * k]);
                float vb = fmaf(acc[2 * k + 1], inv, bb[2 * k + 1]);
                ushort ua = f2bf(va), ub = f2bf(vb);
                float ra = bf2f(ua), rb = bf2f(ub);
                s8[2 * k] += ra;       q8[2 * k] = fmaf(ra, ra, q8[2 * k]);
                s8[2 * k + 1] += rb;   q8[2 * k + 1] = fmaf(rb, rb, q8[2 * k + 1]);
                ow[k] = (unsigned int)ua | ((unsigned int)ub << 16);
            }
            uint4 o; o.x = ow[0]; o.y = ow[1]; o.z = ow[2]; o.w = ow[3];
            ((uint4*)out)[(size_t)n * 16 + c16] = o;
        }
    }
    // stats: col = c16*8+k
    __shared__ float red[4 * 16 * 16];
    if (g == 0) {
#pragma unroll
        for (int k = 0; k < 8; ++k) {
            red[(wv * 16 + c16) * 16 + k] = s8[k];
            red[(wv * 16 + c16) * 16 + 8 + k] = q8[k];
        }
    }
    __syncthreads();
    int t = threadIdx.x;
    if (t < 128) {
        int cr = t >> 3, k = t & 7;
        float ss = red[(0 * 16 + cr) * 16 + k] + red[(1 * 16 + cr) * 16 + k] +
                   red[(2 * 16 + cr) * 16 + k] + red[(3 * 16 + cr) * 16 + k];
        float qq = red[(0 * 16 + cr) * 16 + 8 + k] + red[(1 * 16 + cr) * 16 + 8 + k] +
                   red[(2 * 16 + cr) * 16 + 8 + k] + red[(3 * 16 + cr) * 16 + 8 + k];
        atomicAdd(&stats[t], ss);
        atomicAdd(&stats[128 + t], qq);
    }
}

// ---------------- MFMA GEMM2 + per-block coef from stats + fused layer-2 attn dots ----------
__global__ __launch_bounds__(256) void k_gemm2_mfma(const ushort* __restrict__ X,
                                                    const float* __restrict__ stats,
                                                    const float* __restrict__ gw,
                                                    const float* __restrict__ gb,
                                                    const float* __restrict__ gms,
                                                    const uint4* __restrict__ Bfrag,
                                                    const float* __restrict__ as2,
                                                    const float* __restrict__ ad2,
                                                    ushort* __restrict__ H2,
                                                    float* __restrict__ al_s,
                                                    float* __restrict__ al_d, int Nn) {
    __shared__ __align__(16) float ABs[512];
    {
        int t = threadIdx.x;
        float inv = 1.f / (float)Nn;
        float mean = stats[t] * inv;
        float cm = mean * gms[t];
        float var = stats[256 + t] * inv - 2.f * cm * mean + cm * cm;
        float A = gw[t] * rsqrtf(var + GEPS);
        ABs[t] = A;
        ABs[256 + t] = gb[t] - A * cm;
    }
    __syncthreads();
    int wave = threadIdx.x >> 6, lane = threadIdx.x & 63;
    int q = lane >> 4, m = lane & 15;
    int rowbase = blockIdx.x * 64 + wave * 16;
    int row = rowbase + m;
    bool valid = row < Nn;
    const uint4* xr4 = (const uint4*)((const unsigned int*)X + (size_t)row * 128);
    uint4 xa[8];
#pragma unroll
    for (int kk = 0; kk < 8; ++kk) {
        int k0 = kk * 32 + q * 8;
        xa[kk] = valid ? xr4[k0 >> 3] : make_uint4(0, 0, 0, 0);
    }
    union { short8 s; unsigned int u[4]; } af[8];
#pragma unroll
    for (int kk = 0; kk < 8; ++kk) {
        int k0 = kk * 32 + q * 8;
        float2 x01 = unpack_bf2(xa[kk].x);
        float2 x23 = unpack_bf2(xa[kk].y);
        float2 x45 = unpack_bf2(xa[kk].z);
        float2 x67 = unpack_bf2(xa[kk].w);
        float4 a0 = *(const float4*)(ABs + k0);
        float4 a1 = *(const float4*)(ABs + k0 + 4);
        float4 b0 = *(const float4*)(ABs + 256 + k0);
        float4 b1 = *(const float4*)(ABs + 256 + k0 + 4);
        float v0 = elu_fast(fmaf(a0.x, x01.x, b0.x));
        float v1 = elu_fast(fmaf(a0.y, x01.y, b0.y));
        float v2 = elu_fast(fmaf(a0.z, x23.x, b0.z));
        float v3 = elu_fast(fmaf(a0.w, x23.y, b0.w));
        float v4 = elu_fast(fmaf(a1.x, x45.x, b1.x));
        float v5 = elu_fast(fmaf(a1.y, x45.y, b1.y));
        float v6 = elu_fast(fmaf(a1.z, x67.x, b1.z));
        float v7 = elu_fast(fmaf(a1.w, x67.y, b1.w));
        af[kk].u[0] = pack_bf2(v0, v1);
        af[kk].u[1] = pack_bf2(v2, v3);
        af[kk].u[2] = pack_bf2(v4, v5);
        af[kk].u[3] = pack_bf2(v6, v7);
    }
    floatx4 acc[8];
#pragma unroll
    for (int c = 0; c < 8; ++c) acc[c] = (floatx4){0.f, 0.f, 0.f, 0.f};
#pragma unroll
    for (int kk = 0; kk < 8; ++kk) {
        const uint4* bpf = Bfrag + kk * 64 + lane;
#pragma unroll
        for (int c = 0; c < 8; ++c) {
            union { short8 s; uint4 u; } bf;
            bf.u = bpf[c * 8 * 64];
            acc[c] = __builtin_amdgcn_mfma_f32_16x16x32_bf16(af[kk].s, bf.s, acc[c], 0, 0, 0);
        }
    }
    float a_s[8], a_d[8];
#pragma unroll
    for (int c = 0; c < 8; ++c) {
        a_s[c] = as2[c * 16 + m];
        a_d[c] = ad2[c * 16 + m];
    }
#pragma unroll
    for (int r = 0; r < 4; ++r) {
        int orow = rowbase + q * 4 + r;
        bool vr = orow < Nn;
        ushort us[8];
        float s0 = 0.f, s1 = 0.f, d0 = 0.f, d1 = 0.f;
#pragma unroll
        for (int c = 0; c < 8; ++c) {
            us[c] = f2bf(acc[c][r]);
            float v = bf2f(us[c]);
            if (c < 4) {
                s0 = fmaf(v, a_s[c], s0);
                d0 = fmaf(v, a_d[c], d0);
            } else {
                s1 = fmaf(v, a_s[c], s1);
                d1 = fmaf(v, a_d[c], d1);
            }
        }
#pragma unroll
        for (int o = 1; o < 16; o <<= 1) {
            s0 += __shfl_xor(s0, o);
            s1 += __shfl_xor(s1, o);
            d0 += __shfl_xor(d0, o);
            d1 += __shfl_xor(d1, o);
        }
        if (vr) {
            ushort* op = H2 + (size_t)orow * 128 + m;
#pragma unroll
            for (int c = 0; c < 8; ++c) op[c * 16] = us[c];
            if (m == 0) {
                *(float2*)(al_s + 2 * (size_t)orow) = make_float2(s0, s1);
                *(float2*)(al_d + 2 * (size_t)orow) = make_float2(d0, d1);
            }
        }
    }
}

// ---------------- classifier: per-block coef from stats + fused GraphNorm+ELU ----------------
__global__ __launch_bounds__(256) void k_cls(const ushort* __restrict__ X,
                                             const float* __restrict__ stats,
                                             const float* __restrict__ gw,
                                             const float* __restrict__ gb,
                                             const float* __restrict__ gms,
                                             const float* __restrict__ Wc,
                                             const float* __restrict__ bc,
                                             float* __restrict__ out, int Nn) {
    __shared__ __align__(16) float ls[16 * 132];
    __shared__ __align__(16) float wT[13 * 132];
    __shared__ __align__(16) float ABs[256];
    __shared__ float bS[13];
    int t = threadIdx.x;
    int n0 = blockIdx.x * 16;
    if (t < 128) {
        float inv = 1.f / (float)Nn;
        float mean = stats[t] * inv;
        float cm = mean * gms[t];
        float var = stats[128 + t] * inv - 2.f * cm * mean + cm * cm;
        float A = gw[t] * rsqrtf(var + GEPS);
        ABs[t] = A;
        ABs[128 + t] = gb[t] - A * cm;
    }
    for (int i = t; i < 128 * 13; i += 256) {
        int k = i / 13, j = i - k * 13;
        wT[j * 132 + k] = Wc[i];
    }
    if (t < 13) bS[t] = bc[t];
    __syncthreads();
    const unsigned int* xu = (const unsigned int*)X;
    for (int idx = t; idx < 16 * 64; idx += 256) {
        int r = idx >> 6, ku = idx & 63;
        int row = n0 + r;
        float vx = 0.f, vy = 0.f;
        if (row < Nn) {
            float2 v = unpack_bf2(xu[(size_t)row * 64 + ku]);
            int k = 2 * ku;
            vx = elu_fast(fmaf(ABs[k], v.x, ABs[128 + k]));
            vy = elu_fast(fmaf(ABs[k + 1], v.y, ABs[128 + k + 1]));
        }
        ls[r * 132 + 2 * ku] = vx;
        ls[r * 132 + 2 * ku + 1] = vy;
    }
    __syncthreads();
    if (t < 208) {
        int r = t / 13, j = t - r * 13;
        int row = n0 + r;
        if (row < Nn) {
            float acc = bS[j];
            const float* lr = &ls[r * 132];
            const float* wr = &wT[j * 132];
#pragma unroll 8
            for (int k = 0; k < 128; k += 4) {
                float4 a = *(const float4*)&lr[k];
                float4 b = *(const float4*)&wr[k];
                acc = fmaf(a.x, b.x, fmaf(a.y, b.y, fmaf(a.z, b.z, fmaf(a.w, b.w, acc))));
            }
            out[(size_t)row * 13 + j] = acc;
        }
    }
}

extern "C" void kernel_launch(void* const* d_in, const int* in_sizes, int n_in, void* d_out,
                              int out_size, void* d_ws, size_t ws_size, hipStream_t stream) {
    const float* x = (const float*)d_in[0];
    const int* edge_index = (const int*)d_in[1];
    const float* edge_attr = (const float*)d_in[2];
    const float* W1 = (const float*)d_in[3];
    const float* We1 = (const float*)d_in[4];
    const float* as1 = (const float*)d_in[5];
    const float* ad1 = (const float*)d_in[6];
    const float* ae1 = (const float*)d_in[7];
    const float* b1 = (const float*)d_in[8];
    const float* gn1_w = (const float*)d_in[9];
    const float* gn1_b = (const float*)d_in[10];
    const float* gn1_ms = (const float*)d_in[11];
    const float* W2 = (const float*)d_in[12];
    const float* We2 = (const float*)d_in[13];
    const float* as2 = (const float*)d_in[14];
    const float* ad2 = (const float*)d_in[15];
    const float* ae2 = (const float*)d_in[16];
    const float* b2 = (const float*)d_in[17];
    const float* gn2_w = (const float*)d_in[18];
    const float* gn2_b = (const float*)d_in[19];
    const float* gn2_ms = (const float*)d_in[20];
    const float* Wc = (const float*)d_in[21];
    const float* bc = (const float*)d_in[22];

    const int N = in_sizes[0] / 3;
    const int E = in_sizes[1] / 2;
    const int* srcv = edge_index;
    const int* dstv = edge_index + E;

    // ---- workspace carve (256B-aligned, byte-based) ----
    char* w = (char*)d_ws;
    auto carveB = [&](size_t bytes) -> void* {
        void* p = (void*)w;
        w += ((bytes + 255) / 256) * 256;
        return p;
    };
    // zeroed region first:
    int* deg = (int*)carveB((size_t)N * 4);
    float* ea_sum = (float*)carveB(8);
    float* statsA = (float*)carveB(512 * 4);
    float* statsB = (float*)carveB(256 * 4);
    char* zero_end = w;
    // not zeroed:
    int* row_ptr = (int*)carveB((size_t)(N + 1) * 4);
    int* bsum = (int*)carveB(1024 * 4);
    float4* ed2 = (float4*)carveB((size_t)E * 16);
    uint4* wmp = (uint4*)carveB((size_t)E * 16);
    float4* wm2 = (float4*)wmp;  // layer-2 weights reuse (wmp dead after agg1)
    float* C1 = (float*)carveB(8 * 4);
    float* C2 = (float*)carveB(4 * 4);
    float* Ps = (float*)carveB(12 * 4);
    float* Pd = (float*)carveB(12 * 4);
    float* lE1 = (float*)carveB(4 * 4);
    float* lE2 = (float*)carveB(2 * 4);
    uint4* Bfrag = (uint4*)carveB(4096 * 16);
    float* al_s1 = (float*)carveB((size_t)N * 4 * 4);
    float* al_d1 = (float*)carveB((size_t)N * 4 * 4);
    float* al_s2 = (float*)carveB((size_t)N * 2 * 4);
    float* al_d2 = (float*)carveB((size_t)N * 2 * 4);
    ushort* h2b = (ushort*)carveB((size_t)N * 128 * 2);   // bf16 h2
    ushort* out1b = (ushort*)carveB((size_t)N * 256 * 2); // bf16 layer-1 output
    ushort* out2b = (ushort*)carveB((size_t)N * 128 * 2); // bf16 layer-2 output

    hipMemsetAsync(deg, 0, (size_t)(zero_end - (char*)deg), stream);

    const int nb1 = (N + 1023) / 1024;
    const int ebl = (E + 255) / 256;

    k_pre<<<17 + 256, 256, 0, stream>>>(W1, as1, ad1, edge_attr, dstv, W2, We1, ae1, We2, ae2,
                                        ea_sum, deg, Bfrag, C1, C2, Ps, Pd, E);
    k_scan1<<<nb1, 1024, 0, stream>>>(deg, row_ptr, bsum, N);
    k_scan23<<<nb1, 1024, 0, stream>>>(row_ptr, bsum, ea_sum, C1, C2, Ps, Pd, x, al_s1, al_d1,
                                       lE1, lE2, N, E);
    k_scatfill<<<ebl, 256, 0, stream>>>(dstv, srcv, edge_attr, row_ptr, deg, al_s1, al_d1, C1,
                                        ed2, wmp, E);
    k_agg1<<<AGG1_BLOCKS, 256, 0, stream>>>(x, row_ptr, wmp, al_s1, al_d1, lE1, W1, b1, out1b,
                                            statsA, N);
    k_gemm2_mfma<<<(N + 63) / 64, 256, 0, stream>>>(out1b, statsA, gn1_w, gn1_b, gn1_ms, Bfrag,
                                                    as2, ad2, h2b, al_s2, al_d2, N);
    k_fill2<<<ebl, 256, 0, stream>>>(ed2, al_s2, al_d2, C2, wm2, E);
    k_agg2<<<AGG2_BLOCKS, 256, 0, stream>>>(h2b, row_ptr, wm2, al_s2, al_d2, lE2, b2, out2b,
                                            statsB, N);
    k_cls<<<(N + 15) / 16, 256, 0, stream>>>(out2b, statsB, gn2_w, gn2_b, gn2_ms, Wc, bc,
                                             (float*)d_out, N);
}

// Round 6
// 279.765 us; speedup vs baseline: 1.2427x; 1.2427x over previous
//
#include <hip/hip_runtime.h>
#include <math.h>

#define NEG_SLOPE 0.2f
#define GEPS 1e-5f

typedef __attribute__((ext_vector_type(8))) short short8;
typedef __attribute__((ext_vector_type(4))) float floatx4;

__device__ __forceinline__ float wave_reduce_sum(float v) {
#pragma unroll
    for (int o = 32; o > 0; o >>= 1) v += __shfl_down(v, o);
    return v;
}

__device__ __forceinline__ ushort f2bf(float f) {
    union { float f; unsigned int i; } c;
    c.f = f;
    unsigned int b = c.i;
    b += 0x7fffu + ((b >> 16) & 1u);
    return (ushort)(b >> 16);
}

__device__ __forceinline__ float bf2f(ushort u) {
    union { unsigned int i; float f; } c;
    c.i = (unsigned int)u << 16;
    return c.f;
}

__device__ __forceinline__ float2 unpack_bf2(unsigned int u) {
    union { unsigned int i; float f; } a, b;
    a.i = u << 16;            // low ushort -> even col
    b.i = u & 0xffff0000u;    // high ushort -> odd col
    return make_float2(a.f, b.f);
}

__device__ __forceinline__ unsigned int pack_bf2(float lo, float hi) {
    return (unsigned int)f2bf(lo) | ((unsigned int)f2bf(hi) << 16);
}

__device__ __forceinline__ float lrelu(float v) {
    return (v > 0.f) ? v : v * NEG_SLOPE;
}

__device__ __forceinline__ float elu_fast(float v) {
    return (v > 0.f) ? v : (__expf(v) - 1.f);
}

// ---------------- merged prologue ----------------
// blocks [0, 16)   : W2 -> bf16 MFMA B-fragment layout
// block  16        : attn consts: C1 (We1.ae1), C2 (We2.ae2), P_s1/P_d1 (W1@as1 / W1@ad1, 3/head)
// blocks [17, 273) : edge_attr column sums + degree histogram
__global__ __launch_bounds__(256) void k_pre(
    const float* __restrict__ W1, const float* __restrict__ as1, const float* __restrict__ ad1,
    const float* __restrict__ ea, const int* __restrict__ dst,
    const float* __restrict__ W2, const float* __restrict__ We1,
    const float* __restrict__ ae1, const float* __restrict__ We2,
    const float* __restrict__ ae2,
    float* __restrict__ ea_sum, int* __restrict__ deg, uint4* __restrict__ Bfrag,
    float* __restrict__ C1, float* __restrict__ C2, float* __restrict__ Ps,
    float* __restrict__ Pd, int E) {
    int b = blockIdx.x;
    if (b < 16) {
        int t = b * 256 + threadIdx.x;  // 4096 threads
        int c = t >> 9, kk = (t >> 6) & 7, L = t & 63;
        int q = L >> 4, n = c * 16 + (L & 15);
        int k0 = kk * 32 + q * 8;
        unsigned int u0 = pack_bf2(W2[(k0 + 0) * 128 + n], W2[(k0 + 1) * 128 + n]);
        unsigned int u1 = pack_bf2(W2[(k0 + 2) * 128 + n], W2[(k0 + 3) * 128 + n]);
        unsigned int u2 = pack_bf2(W2[(k0 + 4) * 128 + n], W2[(k0 + 5) * 128 + n]);
        unsigned int u3 = pack_bf2(W2[(k0 + 6) * 128 + n], W2[(k0 + 7) * 128 + n]);
        Bfrag[t] = make_uint4(u0, u1, u2, u3);
        return;
    }
    if (b == 16) {
        int t = threadIdx.x, h = t >> 6, lane = t & 63;
        float p0 = We1[t] * ae1[t];
        float p1 = We1[256 + t] * ae1[t];
        p0 = wave_reduce_sum(p0);
        p1 = wave_reduce_sum(p1);
        if (lane == 0) { C1[h] = p0; C1[4 + h] = p1; }
        float av = as1[t], dv = ad1[t];
#pragma unroll
        for (int k = 0; k < 3; ++k) {
            float wv = W1[k * 256 + t];
            float ps = wave_reduce_sum(wv * av);
            float pd = wave_reduce_sum(wv * dv);
            if (lane == 0) { Ps[h * 3 + k] = ps; Pd[h * 3 + k] = pd; }
        }
        if (t < 128) {
            float q0 = We2[t] * ae2[t];
            float q1 = We2[128 + t] * ae2[t];
            q0 = wave_reduce_sum(q0);
            q1 = wave_reduce_sum(q1);
            if (lane == 0) { C2[h] = q0; C2[2 + h] = q1; }
        }
        return;
    }
    b -= 17;
    const float2* ea2 = (const float2*)ea;
    float s0 = 0.f, s1 = 0.f;
    for (int e = b * 256 + threadIdx.x; e < E; e += 256 * 256) {
        float2 v = ea2[e];
        s0 += v.x; s1 += v.y;
        atomicAdd(&deg[dst[e]], 1);
    }
    s0 = wave_reduce_sum(s0);
    s1 = wave_reduce_sum(s1);
    if ((threadIdx.x & 63) == 0) {
        atomicAdd(&ea_sum[0], s0);
        atomicAdd(&ea_sum[1], s1);
    }
}

// ---------------- CSR row_ptr scan (block-local) ----------------
__global__ void k_scan1(const int* __restrict__ deg, int* __restrict__ row_ptr,
                        int* __restrict__ bsum, int N) {
    __shared__ int tmp[1024];
    int tid = threadIdx.x;
    int i = blockIdx.x * 1024 + tid;
    int v = (i < N) ? deg[i] : 0;
    tmp[tid] = v;
    __syncthreads();
#pragma unroll
    for (int off = 1; off < 1024; off <<= 1) {
        int t = (tid >= off) ? tmp[tid - off] : 0;
        __syncthreads();
        tmp[tid] += t;
        __syncthreads();
    }
    if (i < N) row_ptr[i + 1] = tmp[tid];
    if (tid == 1023) bsum[blockIdx.x] = tmp[1023];
}

// block prefix recomputed per block in one wave (nb1 <= 64), then applied.
// also: lE1/lE2 self-loop consts (needs ea_sum), and al_s1/al_d1 fill (x . P_s/P_d per head).
__global__ void k_scan23(int* __restrict__ row_ptr, const int* __restrict__ bsum,
                         const float* __restrict__ ea_sum, const float* __restrict__ C1,
                         const float* __restrict__ C2, const float* __restrict__ Ps,
                         const float* __restrict__ Pd, const float* __restrict__ x,
                         float* __restrict__ al_s1, float* __restrict__ al_d1,
                         float* __restrict__ lE1, float* __restrict__ lE2, int N, int E) {
    __shared__ int off_s;
    int t = threadIdx.x;
    if (blockIdx.x == 0 && t >= 64 && t < 68) {
        int k = t - 64;
        float m0 = ea_sum[0] / (float)E, m1 = ea_sum[1] / (float)E;
        lE1[k] = m0 * C1[k] + m1 * C1[4 + k];
        if (k < 2) lE2[k] = m0 * C2[k] + m1 * C2[2 + k];
    }
    if (t < 64) {
        int v = (t < blockIdx.x) ? bsum[t] : 0;
#pragma unroll
        for (int o = 32; o > 0; o >>= 1) v += __shfl_xor(v, o);
        if (t == 0) off_s = v;
    }
    __syncthreads();
    int off = off_s;
    int i = blockIdx.x * 1024 + t;
    if (i == 0) row_ptr[0] = 0;
    if (i < N) {
        row_ptr[i + 1] += off;
        float x0 = x[3 * i], x1 = x[3 * i + 1], x2 = x[3 * i + 2];
        float4 sv, dv;
        sv.x = fmaf(x0, Ps[0], fmaf(x1, Ps[1], x2 * Ps[2]));
        sv.y = fmaf(x0, Ps[3], fmaf(x1, Ps[4], x2 * Ps[5]));
        sv.z = fmaf(x0, Ps[6], fmaf(x1, Ps[7], x2 * Ps[8]));
        sv.w = fmaf(x0, Ps[9], fmaf(x1, Ps[10], x2 * Ps[11]));
        dv.x = fmaf(x0, Pd[0], fmaf(x1, Pd[1], x2 * Pd[2]));
        dv.y = fmaf(x0, Pd[3], fmaf(x1, Pd[4], x2 * Pd[5]));
        dv.z = fmaf(x0, Pd[6], fmaf(x1, Pd[7], x2 * Pd[8]));
        dv.w = fmaf(x0, Pd[9], fmaf(x1, Pd[10], x2 * Pd[11]));
        *(float4*)(al_s1 + 4 * (size_t)i) = sv;
        *(float4*)(al_d1 + 4 * (size_t)i) = dv;
    }
}

// ---------------- CSR scatter fused with layer-1 edge weights ----------------
__global__ void k_scatfill(const int* __restrict__ dst, const int* __restrict__ src,
                           const float* __restrict__ ea, const int* __restrict__ row_ptr,
                           int* __restrict__ deg, const float* __restrict__ al_s1,
                           const float* __restrict__ al_d1, const float* __restrict__ C1,
                           float4* __restrict__ ed2, uint4* __restrict__ wmp, int E) {
    int e = blockIdx.x * 256 + threadIdx.x;
    if (e >= E) return;
    int d = dst[e];
    int r = atomicSub(&deg[d], 1);
    int slot = row_ptr[d] + r - 1;
    int s = src[e];
    float2 v = ((const float2*)ea)[e];
    float4 as = *(const float4*)(al_s1 + 4 * (size_t)s);
    float4 ad = *(const float4*)(al_d1 + 4 * (size_t)d);
    float w0 = __expf(lrelu(as.x + ad.x + v.x * C1[0] + v.y * C1[4]));
    float w1 = __expf(lrelu(as.y + ad.y + v.x * C1[1] + v.y * C1[5]));
    float w2 = __expf(lrelu(as.z + ad.z + v.x * C1[2] + v.y * C1[6]));
    float w3 = __expf(lrelu(as.w + ad.w + v.x * C1[3] + v.y * C1[7]));
    ed2[slot] = make_float4(__int_as_float(s), __int_as_float(d), v.x, v.y);
    wmp[slot] = make_uint4((unsigned int)s, pack_bf2(w0, w1), pack_bf2(w2, w3), 0u);
}

// ---------------- layer-2 edge-weight fill (CSR order) ----------------
__global__ void k_fill2(const float4* __restrict__ ed2, const float* __restrict__ al_s2,
                        const float* __restrict__ al_d2, const float* __restrict__ C2,
                        float4* __restrict__ wm2, int E) {
    int e = blockIdx.x * 256 + threadIdx.x;
    if (e >= E) return;
    float4 m = ed2[e];
    int s = __float_as_int(m.x), d = __float_as_int(m.y);
    float2 as = *(const float2*)(al_s2 + 2 * (size_t)s);
    float2 ad = *(const float2*)(al_d2 + 2 * (size_t)d);
    float wA = __expf(lrelu(as.x + ad.x + m.z * C2[0] + m.w * C2[2]));
    float wB = __expf(lrelu(as.y + ad.y + m.z * C2[1] + m.w * C2[3]));
    wm2[e] = make_float4(m.x, wA, wB, 0.f);
}

// ---------------- layer-1 aggregation in x-space (linearity of W1), ONE-PASS ----------
// z_h = sum_e w_eh * x[src_e] (+ self), out[n] = (z_h . W1col)/dsum_h + b1. 12B gathers.
// block = 8 nodes x 32 lanes. Reduce-scatter: 24 shuffles/node (not 80).
__global__ __launch_bounds__(256) void k_agg1(const float* __restrict__ x,
                                              const int* __restrict__ row_ptr,
                                              const uint4* __restrict__ wmp,
                                              const float* __restrict__ al_s,
                                              const float* __restrict__ al_d,
                                              const float* __restrict__ lE,
                                              const float* __restrict__ W1,
                                              const float* __restrict__ bias,
                                              ushort* __restrict__ out, int N) {
    int l = threadIdx.x & 31;
    int grp = threadIdx.x >> 5;
    int n = blockIdx.x * 8 + grp;
    if (n >= N) return;
    int c0 = l * 8;
    int hh = l >> 3;  // head of owned columns
    // reg-resident W1 columns + bias for the 8 owned cols
    float4 wa0 = *(const float4*)(W1 + c0);
    float4 wa1 = *(const float4*)(W1 + c0 + 4);
    float4 wb0 = *(const float4*)(W1 + 256 + c0);
    float4 wb1 = *(const float4*)(W1 + 256 + c0 + 4);
    float4 wc0 = *(const float4*)(W1 + 512 + c0);
    float4 wc1 = *(const float4*)(W1 + 512 + c0 + 4);
    float4 bv0 = *(const float4*)(bias + c0);
    float4 bv1 = *(const float4*)(bias + c0 + 4);
    float4 asn = *(const float4*)(al_s + 4 * (size_t)n);
    float4 adn = *(const float4*)(al_d + 4 * (size_t)n);
    float ws0 = __expf(lrelu(asn.x + adn.x + lE[0]));
    float ws1 = __expf(lrelu(asn.y + adn.y + lE[1]));
    float ws2 = __expf(lrelu(asn.z + adn.z + lE[2]));
    float ws3 = __expf(lrelu(asn.w + adn.w + lE[3]));
    float z[12];
    float ds[4];
#pragma unroll
    for (int k = 0; k < 12; ++k) z[k] = 0.f;
#pragma unroll
    for (int k = 0; k < 4; ++k) ds[k] = 0.f;
    int i0 = row_ptr[n];
    int cnt = row_ptr[n + 1] - i0;
    for (int j = l; j < cnt; j += 32) {
        uint4 me = wmp[i0 + j];
        int s = (int)me.x;
        float xs0 = x[3 * s], xs1 = x[3 * s + 1], xs2 = x[3 * s + 2];
        float2 w01 = unpack_bf2(me.y);
        float2 w23 = unpack_bf2(me.z);
        z[0] = fmaf(w01.x, xs0, z[0]); z[1] = fmaf(w01.x, xs1, z[1]); z[2] = fmaf(w01.x, xs2, z[2]);
        z[3] = fmaf(w01.y, xs0, z[3]); z[4] = fmaf(w01.y, xs1, z[4]); z[5] = fmaf(w01.y, xs2, z[5]);
        z[6] = fmaf(w23.x, xs0, z[6]); z[7] = fmaf(w23.x, xs1, z[7]); z[8] = fmaf(w23.x, xs2, z[8]);
        z[9] = fmaf(w23.y, xs0, z[9]); z[10] = fmaf(w23.y, xs1, z[10]); z[11] = fmaf(w23.y, xs2, z[11]);
        ds[0] += w01.x; ds[1] += w01.y; ds[2] += w23.x; ds[3] += w23.y;
    }
    // reduce-scatter stage 1 (xor 16): lo lanes keep heads {0,1}, hi lanes heads {2,3}
    bool hi16 = (l & 16) != 0;
    float a0, a1, a2, a3, a4, a5, a6, a7, gv, rv;
    gv = hi16 ? z[0] : z[6];  rv = __shfl_xor(gv, 16); a0 = (hi16 ? z[6] : z[0]) + rv;
    gv = hi16 ? z[1] : z[7];  rv = __shfl_xor(gv, 16); a1 = (hi16 ? z[7] : z[1]) + rv;
    gv = hi16 ? z[2] : z[8];  rv = __shfl_xor(gv, 16); a2 = (hi16 ? z[8] : z[2]) + rv;
    gv = hi16 ? z[3] : z[9];  rv = __shfl_xor(gv, 16); a3 = (hi16 ? z[9] : z[3]) + rv;
    gv = hi16 ? z[4] : z[10]; rv = __shfl_xor(gv, 16); a4 = (hi16 ? z[10] : z[4]) + rv;
    gv = hi16 ? z[5] : z[11]; rv = __shfl_xor(gv, 16); a5 = (hi16 ? z[11] : z[5]) + rv;
    gv = hi16 ? ds[0] : ds[2]; rv = __shfl_xor(gv, 16); a6 = (hi16 ? ds[2] : ds[0]) + rv;
    gv = hi16 ? ds[1] : ds[3]; rv = __shfl_xor(gv, 16); a7 = (hi16 ? ds[3] : ds[1]) + rv;
    // stage 2 (xor 8): keep own head (a0..a2 = headA z, a3..a5 = headB z, a6/a7 = dsA/dsB)
    bool hi8 = (l & 8) != 0;
    float c0v, c1v, c2v, c3v;
    gv = hi8 ? a0 : a3; rv = __shfl_xor(gv, 8); c0v = (hi8 ? a3 : a0) + rv;
    gv = hi8 ? a1 : a4; rv = __shfl_xor(gv, 8); c1v = (hi8 ? a4 : a1) + rv;
    gv = hi8 ? a2 : a5; rv = __shfl_xor(gv, 8); c2v = (hi8 ? a5 : a2) + rv;
    gv = hi8 ? a6 : a7; rv = __shfl_xor(gv, 8); c3v = (hi8 ? a7 : a6) + rv;
    // stages 3-5: full butterfly within the 8-lane head group
#pragma unroll
    for (int o = 4; o > 0; o >>= 1) {
        c0v += __shfl_xor(c0v, o);
        c1v += __shfl_xor(c1v, o);
        c2v += __shfl_xor(c2v, o);
        c3v += __shfl_xor(c3v, o);
    }
    // self-loop contribution for the owned head
    float wsh = (hh == 0) ? ws0 : (hh == 1) ? ws1 : (hh == 2) ? ws2 : ws3;
    float xn0 = x[3 * n], xn1 = x[3 * n + 1], xn2 = x[3 * n + 2];
    c0v = fmaf(wsh, xn0, c0v);
    c1v = fmaf(wsh, xn1, c1v);
    c2v = fmaf(wsh, xn2, c2v);
    c3v += wsh;
    float inv = 1.f / c3v;
    float v0 = fmaf(fmaf(c0v, wa0.x, fmaf(c1v, wb0.x, c2v * wc0.x)), inv, bv0.x);
    float v1 = fmaf(fmaf(c0v, wa0.y, fmaf(c1v, wb0.y, c2v * wc0.y)), inv, bv0.y);
    float v2 = fmaf(fmaf(c0v, wa0.z, fmaf(c1v, wb0.z, c2v * wc0.z)), inv, bv0.z);
    float v3 = fmaf(fmaf(c0v, wa0.w, fmaf(c1v, wb0.w, c2v * wc0.w)), inv, bv0.w);
    float v4 = fmaf(fmaf(c0v, wa1.x, fmaf(c1v, wb1.x, c2v * wc1.x)), inv, bv1.x);
    float v5 = fmaf(fmaf(c0v, wa1.y, fmaf(c1v, wb1.y, c2v * wc1.y)), inv, bv1.y);
    float v6 = fmaf(fmaf(c0v, wa1.z, fmaf(c1v, wb1.z, c2v * wc1.z)), inv, bv1.z);
    float v7 = fmaf(fmaf(c0v, wa1.w, fmaf(c1v, wb1.w, c2v * wc1.w)), inv, bv1.w);
    uint4 o;
    o.x = pack_bf2(v0, v1);
    o.y = pack_bf2(v2, v3);
    o.z = pack_bf2(v4, v5);
    o.w = pack_bf2(v6, v7);
    ((uint4*)out)[(size_t)n * 32 + l] = o;
}

// ---------------- layer-2 aggregation: one wave/node, 4 groups, 4-stage pipeline --------
__global__ __launch_bounds__(256) void k_agg2(const ushort* __restrict__ h2,
                                              const int* __restrict__ row_ptr,
                                              const float4* __restrict__ wm,
                                              const float* __restrict__ al_s,
                                              const float* __restrict__ al_d,
                                              const float* __restrict__ lE,
                                              const float* __restrict__ bias,
                                              ushort* __restrict__ out, int N) {
    int n = blockIdx.x * 4 + (threadIdx.x >> 6);
    if (n >= N) return;
    int lane = threadIdx.x & 63;
    int g = lane >> 4, c16 = lane & 15;
    bool hi = c16 >= 8;
    const uint4* h2u4 = (const uint4*)h2;
    float2 ad = *(const float2*)(al_d + 2 * (size_t)n);
    float2 as = *(const float2*)(al_s + 2 * (size_t)n);
    float wsA = __expf(lrelu(as.x + ad.x + lE[0]));
    float wsB = __expf(lrelu(as.y + ad.y + lE[1]));
    uint4 hs = h2u4[(size_t)n * 16 + c16];
    float wself = (g == 0) ? (hi ? wsB : wsA) : 0.f;
    float dsum = wself;
    float acc[8];
    {
        float2 t0 = unpack_bf2(hs.x), t1 = unpack_bf2(hs.y);
        float2 t2 = unpack_bf2(hs.z), t3 = unpack_bf2(hs.w);
        acc[0] = wself * t0.x; acc[1] = wself * t0.y;
        acc[2] = wself * t1.x; acc[3] = wself * t1.y;
        acc[4] = wself * t2.x; acc[5] = wself * t2.y;
        acc[6] = wself * t3.x; acc[7] = wself * t3.y;
    }
    int i0 = row_ptr[n];
    int cnt = row_ptr[n + 1] - i0;
    if (cnt > 0) {
        int last = cnt - 1;
        int nit = (cnt + 3) >> 2;
        int j0 = g;      float mkA = 1.f; if (j0 > last) { j0 = last; mkA = 0.f; }
        int j1 = 4 + g;  float mkB = 1.f; if (j1 > last) { j1 = last; mkB = 0.f; }
        int j2 = 8 + g;  float mkC = 1.f; if (j2 > last) { j2 = last; mkC = 0.f; }
        int j3 = 12 + g; float mkD = 1.f; if (j3 > last) { j3 = last; mkD = 0.f; }
        float4 meA = wm[i0 + j0];
        float4 meB = wm[i0 + j1];
        float4 meC = wm[i0 + j2];
        float4 meD = wm[i0 + j3];
        uint4 gvA = h2u4[(size_t)__float_as_int(meA.x) * 16 + c16];
        uint4 gvB = h2u4[(size_t)__float_as_int(meB.x) * 16 + c16];
        uint4 gvC = h2u4[(size_t)__float_as_int(meC.x) * 16 + c16];
        for (int it = 0; it < nit - 1; ++it) {
            uint4 gvD = h2u4[(size_t)__float_as_int(meD.x) * 16 + c16];
            int jn = 4 * (it + 4) + g;
            float mn = 1.f;
            if (jn > last) { jn = last; mn = 0.f; }
            float4 meE = wm[i0 + jn];
            float wg = (hi ? meA.z : meA.y) * mkA;
            dsum += wg;
            float2 u;
            u = unpack_bf2(gvA.x); acc[0] = fmaf(wg, u.x, acc[0]); acc[1] = fmaf(wg, u.y, acc[1]);
            u = unpack_bf2(gvA.y); acc[2] = fmaf(wg, u.x, acc[2]); acc[3] = fmaf(wg, u.y, acc[3]);
            u = unpack_bf2(gvA.z); acc[4] = fmaf(wg, u.x, acc[4]); acc[5] = fmaf(wg, u.y, acc[5]);
            u = unpack_bf2(gvA.w); acc[6] = fmaf(wg, u.x, acc[6]); acc[7] = fmaf(wg, u.y, acc[7]);
            meA = meB; meB = meC; meC = meD; meD = meE;
            gvA = gvB; gvB = gvC; gvC = gvD;
            mkA = mkB; mkB = mkC; mkC = mkD; mkD = mn;
        }
        float wg = (hi ? meA.z : meA.y) * mkA;
        dsum += wg;
        float2 u;
        u = unpack_bf2(gvA.x); acc[0] = fmaf(wg, u.x, acc[0]); acc[1] = fmaf(wg, u.y, acc[1]);
        u = unpack_bf2(gvA.y); acc[2] = fmaf(wg, u.x, acc[2]); acc[3] = fmaf(wg, u.y, acc[3]);
        u = unpack_bf2(gvA.z); acc[4] = fmaf(wg, u.x, acc[4]); acc[5] = fmaf(wg, u.y, acc[5]);
        u = unpack_bf2(gvA.w); acc[6] = fmaf(wg, u.x, acc[6]); acc[7] = fmaf(wg, u.y, acc[7]);
    }
#pragma unroll
    for (int k = 0; k < 8; ++k) {
        acc[k] += __shfl_xor(acc[k], 16);
        acc[k] += __shfl_xor(acc[k], 32);
    }
    dsum += __shfl_xor(dsum, 16);
    dsum += __shfl_xor(dsum, 32);
    if (g == 0) {
        float inv = 1.f / dsum;
        const float* bp = bias + c16 * 8;
        float4 b0 = *(const float4*)bp;
        float4 b1 = *(const float4*)(bp + 4);
        uint4 o;
        o.x = pack_bf2(fmaf(acc[0], inv, b0.x), fmaf(acc[1], inv, b0.y));
        o.y = pack_bf2(fmaf(acc[2], inv, b0.z), fmaf(acc[3], inv, b0.w));
        o.z = pack_bf2(fmaf(acc[4], inv, b1.x), fmaf(acc[5], inv, b1.y));
        o.w = pack_bf2(fmaf(acc[6], inv, b1.z), fmaf(acc[7], inv, b1.w));
        ((uint4*)out)[(size_t)n * 16 + c16] = o;
    }
}

// ---------------- GraphNorm column stats: uint4 streaming + LDS tree + few atomics ----------
template <int C4>
__global__ __launch_bounds__(256) void k_stats_bf(const ushort* __restrict__ x,
                                                  float* __restrict__ stats, int rows) {
    const int C = C4 * 8;
    const int RG = 256 / C4;
    int t = threadIdx.x;
    int c = t & (C4 - 1);
    int rg = t / C4;
    int rpb = (rows + gridDim.x - 1) / gridDim.x;
    int r0 = blockIdx.x * rpb;
    int r1 = r0 + rpb;
    if (r1 > rows) r1 = rows;
    const uint4* xu = (const uint4*)x;
    float s[8] = {0.f, 0.f, 0.f, 0.f, 0.f, 0.f, 0.f, 0.f};
    float q[8] = {0.f, 0.f, 0.f, 0.f, 0.f, 0.f, 0.f, 0.f};
    for (int r = r0 + rg; r < r1; r += RG) {
        uint4 v = xu[(size_t)r * C4 + c];
        float2 a0 = unpack_bf2(v.x), a1 = unpack_bf2(v.y);
        float2 a2 = unpack_bf2(v.z), a3 = unpack_bf2(v.w);
        s[0] += a0.x; q[0] = fmaf(a0.x, a0.x, q[0]);
        s[1] += a0.y; q[1] = fmaf(a0.y, a0.y, q[1]);
        s[2] += a1.x; q[2] = fmaf(a1.x, a1.x, q[2]);
        s[3] += a1.y; q[3] = fmaf(a1.y, a1.y, q[3]);
        s[4] += a2.x; q[4] = fmaf(a2.x, a2.x, q[4]);
        s[5] += a2.y; q[5] = fmaf(a2.y, a2.y, q[5]);
        s[6] += a3.x; q[6] = fmaf(a3.x, a3.x, q[6]);
        s[7] += a3.y; q[7] = fmaf(a3.y, a3.y, q[7]);
    }
    __shared__ float ls[256 * 16];
#pragma unroll
    for (int k = 0; k < 8; ++k) {
        ls[t * 16 + k] = s[k];
        ls[t * 16 + 8 + k] = q[k];
    }
    __syncthreads();
    if (t < C) {
        int cc = t >> 3, k = t & 7;
        float ssum = 0.f, qsum = 0.f;
#pragma unroll
        for (int g = 0; g < RG; ++g) {
            ssum += ls[(g * C4 + cc) * 16 + k];
            qsum += ls[(g * C4 + cc) * 16 + 8 + k];
        }
        atomicAdd(&stats[t], ssum);
        atomicAdd(&stats[C + t], qsum);
    }
}

// ---------------- MFMA GEMM2 + per-block coef from stats + fused layer-2 attn dots ----------
__global__ __launch_bounds__(256) void k_gemm2_mfma(const ushort* __restrict__ X,
                                                    const float* __restrict__ stats,
                                                    const float* __restrict__ gw,
                                                    const float* __restrict__ gb,
                                                    const float* __restrict__ gms,
                                                    const uint4* __restrict__ Bfrag,
                                                    const float* __restrict__ as2,
                                                    const float* __restrict__ ad2,
                                                    ushort* __restrict__ H2,
                                                    float* __restrict__ al_s,
                                                    float* __restrict__ al_d, int Nn) {
    __shared__ __align__(16) float ABs[512];
    {
        int t = threadIdx.x;
        float inv = 1.f / (float)Nn;
        float mean = stats[t] * inv;
        float cm = mean * gms[t];
        float var = stats[256 + t] * inv - 2.f * cm * mean + cm * cm;
        float A = gw[t] * rsqrtf(var + GEPS);
        ABs[t] = A;
        ABs[256 + t] = gb[t] - A * cm;
    }
    __syncthreads();
    int wave = threadIdx.x >> 6, lane = threadIdx.x & 63;
    int q = lane >> 4, m = lane & 15;
    int rowbase = blockIdx.x * 64 + wave * 16;
    int row = rowbase + m;
    bool valid = row < Nn;
    const uint4* xr4 = (const uint4*)((const unsigned int*)X + (size_t)row * 128);
    uint4 xa[8];
#pragma unroll
    for (int kk = 0; kk < 8; ++kk) {
        int k0 = kk * 32 + q * 8;
        xa[kk] = valid ? xr4[k0 >> 3] : make_uint4(0, 0, 0, 0);
    }
    union { short8 s; unsigned int u[4]; } af[8];
#pragma unroll
    for (int kk = 0; kk < 8; ++kk) {
        int k0 = kk * 32 + q * 8;
        float2 x01 = unpack_bf2(xa[kk].x);
        float2 x23 = unpack_bf2(xa[kk].y);
        float2 x45 = unpack_bf2(xa[kk].z);
        float2 x67 = unpack_bf2(xa[kk].w);
        float4 a0 = *(const float4*)(ABs + k0);
        float4 a1 = *(const float4*)(ABs + k0 + 4);
        float4 b0 = *(const float4*)(ABs + 256 + k0);
        float4 b1 = *(const float4*)(ABs + 256 + k0 + 4);
        float v0 = elu_fast(fmaf(a0.x, x01.x, b0.x));
        float v1 = elu_fast(fmaf(a0.y, x01.y, b0.y));
        float v2 = elu_fast(fmaf(a0.z, x23.x, b0.z));
        float v3 = elu_fast(fmaf(a0.w, x23.y, b0.w));
        float v4 = elu_fast(fmaf(a1.x, x45.x, b1.x));
        float v5 = elu_fast(fmaf(a1.y, x45.y, b1.y));
        float v6 = elu_fast(fmaf(a1.z, x67.x, b1.z));
        float v7 = elu_fast(fmaf(a1.w, x67.y, b1.w));
        af[kk].u[0] = pack_bf2(v0, v1);
        af[kk].u[1] = pack_bf2(v2, v3);
        af[kk].u[2] = pack_bf2(v4, v5);
        af[kk].u[3] = pack_bf2(v6, v7);
    }
    floatx4 acc[8];
#pragma unroll
    for (int c = 0; c < 8; ++c) acc[c] = (floatx4){0.f, 0.f, 0.f, 0.f};
#pragma unroll
    for (int kk = 0; kk < 8; ++kk) {
        const uint4* bpf = Bfrag + kk * 64 + lane;
#pragma unroll
        for (int c = 0; c < 8; ++c) {
            union { short8 s; uint4 u; } bf;
            bf.u = bpf[c * 8 * 64];
            acc[c] = __builtin_amdgcn_mfma_f32_16x16x32_bf16(af[kk].s, bf.s, acc[c], 0, 0, 0);
        }
    }
    float a_s[8], a_d[8];
#pragma unroll
    for (int c = 0; c < 8; ++c) {
        a_s[c] = as2[c * 16 + m];
        a_d[c] = ad2[c * 16 + m];
    }
#pragma unroll
    for (int r = 0; r < 4; ++r) {
        int orow = rowbase + q * 4 + r;
        bool vr = orow < Nn;
        ushort us[8];
        float s0 = 0.f, s1 = 0.f, d0 = 0.f, d1 = 0.f;
#pragma unroll
        for (int c = 0; c < 8; ++c) {
            us[c] = f2bf(acc[c][r]);
            float v = bf2f(us[c]);
            if (c < 4) {
                s0 = fmaf(v, a_s[c], s0);
                d0 = fmaf(v, a_d[c], d0);
            } else {
                s1 = fmaf(v, a_s[c], s1);
                d1 = fmaf(v, a_d[c], d1);
            }
        }
#pragma unroll
        for (int o = 1; o < 16; o <<= 1) {
            s0 += __shfl_xor(s0, o);
            s1 += __shfl_xor(s1, o);
            d0 += __shfl_xor(d0, o);
            d1 += __shfl_xor(d1, o);
        }
        if (vr) {
            ushort* op = H2 + (size_t)orow * 128 + m;
#pragma unroll
            for (int c = 0; c < 8; ++c) op[c * 16] = us[c];
            if (m == 0) {
                *(float2*)(al_s + 2 * (size_t)orow) = make_float2(s0, s1);
                *(float2*)(al_d + 2 * (size_t)orow) = make_float2(d0, d1);
            }
        }
    }
}

// ---------------- classifier: per-block coef from stats + fused GraphNorm+ELU ----------------
__global__ __launch_bounds__(256) void k_cls(const ushort* __restrict__ X,
                                             const float* __restrict__ stats,
                                             const float* __restrict__ gw,
                                             const float* __restrict__ gb,
                                             const float* __restrict__ gms,
                                             const float* __restrict__ Wc,
                                             const float* __restrict__ bc,
                                             float* __restrict__ out, int Nn) {
    __shared__ __align__(16) float ls[16 * 132];
    __shared__ __align__(16) float wT[13 * 132];
    __shared__ __align__(16) float ABs[256];
    __shared__ float bS[13];
    int t = threadIdx.x;
    int n0 = blockIdx.x * 16;
    if (t < 128) {
        float inv = 1.f / (float)Nn;
        float mean = stats[t] * inv;
        float cm = mean * gms[t];
        float var = stats[128 + t] * inv - 2.f * cm * mean + cm * cm;
        float A = gw[t] * rsqrtf(var + GEPS);
        ABs[t] = A;
        ABs[128 + t] = gb[t] - A * cm;
    }
    for (int i = t; i < 128 * 13; i += 256) {
        int k = i / 13, j = i - k * 13;
        wT[j * 132 + k] = Wc[i];
    }
    if (t < 13) bS[t] = bc[t];
    __syncthreads();
    const unsigned int* xu = (const unsigned int*)X;
    for (int idx = t; idx < 16 * 64; idx += 256) {
        int r = idx >> 6, ku = idx & 63;
        int row = n0 + r;
        float vx = 0.f, vy = 0.f;
        if (row < Nn) {
            float2 v = unpack_bf2(xu[(size_t)row * 64 + ku]);
            int k = 2 * ku;
            vx = elu_fast(fmaf(ABs[k], v.x, ABs[128 + k]));
            vy = elu_fast(fmaf(ABs[k + 1], v.y, ABs[128 + k + 1]));
        }
        ls[r * 132 + 2 * ku] = vx;
        ls[r * 132 + 2 * ku + 1] = vy;
    }
    __syncthreads();
    if (t < 208) {
        int r = t / 13, j = t - r * 13;
        int row = n0 + r;
        if (row < Nn) {
            float acc = bS[j];
            const float* lr = &ls[r * 132];
            const float* wr = &wT[j * 132];
#pragma unroll 8
            for (int k = 0; k < 128; k += 4) {
                float4 a = *(const float4*)&lr[k];
                float4 b = *(const float4*)&wr[k];
                acc = fmaf(a.x, b.x, fmaf(a.y, b.y, fmaf(a.z, b.z, fmaf(a.w, b.w, acc))));
            }
            out[(size_t)row * 13 + j] = acc;
        }
    }
}

extern "C" void kernel_launch(void* const* d_in, const int* in_sizes, int n_in, void* d_out,
                              int out_size, void* d_ws, size_t ws_size, hipStream_t stream) {
    const float* x = (const float*)d_in[0];
    const int* edge_index = (const int*)d_in[1];
    const float* edge_attr = (const float*)d_in[2];
    const float* W1 = (const float*)d_in[3];
    const float* We1 = (const float*)d_in[4];
    const float* as1 = (const float*)d_in[5];
    const float* ad1 = (const float*)d_in[6];
    const float* ae1 = (const float*)d_in[7];
    const float* b1 = (const float*)d_in[8];
    const float* gn1_w = (const float*)d_in[9];
    const float* gn1_b = (const float*)d_in[10];
    const float* gn1_ms = (const float*)d_in[11];
    const float* W2 = (const float*)d_in[12];
    const float* We2 = (const float*)d_in[13];
    const float* as2 = (const float*)d_in[14];
    const float* ad2 = (const float*)d_in[15];
    const float* ae2 = (const float*)d_in[16];
    const float* b2 = (const float*)d_in[17];
    const float* gn2_w = (const float*)d_in[18];
    const float* gn2_b = (const float*)d_in[19];
    const float* gn2_ms = (const float*)d_in[20];
    const float* Wc = (const float*)d_in[21];
    const float* bc = (const float*)d_in[22];

    const int N = in_sizes[0] / 3;
    const int E = in_sizes[1] / 2;
    const int* srcv = edge_index;
    const int* dstv = edge_index + E;

    // ---- workspace carve (256B-aligned, byte-based) ----
    char* w = (char*)d_ws;
    auto carveB = [&](size_t bytes) -> void* {
        void* p = (void*)w;
        w += ((bytes + 255) / 256) * 256;
        return p;
    };
    // zeroed region first:
    int* deg = (int*)carveB((size_t)N * 4);
    float* ea_sum = (float*)carveB(8);
    float* statsA = (float*)carveB(512 * 4);
    float* statsB = (float*)carveB(256 * 4);
    char* zero_end = w;
    // not zeroed:
    int* row_ptr = (int*)carveB((size_t)(N + 1) * 4);
    int* bsum = (int*)carveB(1024 * 4);
    float4* ed2 = (float4*)carveB((size_t)E * 16);
    uint4* wmp = (uint4*)carveB((size_t)E * 16);
    float4* wm2 = (float4*)wmp;  // layer-2 weights reuse (wmp dead after agg1)
    float* C1 = (float*)carveB(8 * 4);
    float* C2 = (float*)carveB(4 * 4);
    float* Ps = (float*)carveB(12 * 4);
    float* Pd = (float*)carveB(12 * 4);
    float* lE1 = (float*)carveB(4 * 4);
    float* lE2 = (float*)carveB(2 * 4);
    uint4* Bfrag = (uint4*)carveB(4096 * 16);
    float* al_s1 = (float*)carveB((size_t)N * 4 * 4);
    float* al_d1 = (float*)carveB((size_t)N * 4 * 4);
    float* al_s2 = (float*)carveB((size_t)N * 2 * 4);
    float* al_d2 = (float*)carveB((size_t)N * 2 * 4);
    ushort* h2b = (ushort*)carveB((size_t)N * 128 * 2);   // bf16 h2
    ushort* out1b = (ushort*)carveB((size_t)N * 256 * 2); // bf16 layer-1 output
    ushort* out2b = (ushort*)carveB((size_t)N * 128 * 2); // bf16 layer-2 output

    hipMemsetAsync(deg, 0, (size_t)(zero_end - (char*)deg), stream);

    const int nb1 = (N + 1023) / 1024;
    const int ebl = (E + 255) / 256;

    k_pre<<<17 + 256, 256, 0, stream>>>(W1, as1, ad1, edge_attr, dstv, W2, We1, ae1, We2, ae2,
                                        ea_sum, deg, Bfrag, C1, C2, Ps, Pd, E);
    k_scan1<<<nb1, 1024, 0, stream>>>(deg, row_ptr, bsum, N);
    k_scan23<<<nb1, 1024, 0, stream>>>(row_ptr, bsum, ea_sum, C1, C2, Ps, Pd, x, al_s1, al_d1,
                                       lE1, lE2, N, E);
    k_scatfill<<<ebl, 256, 0, stream>>>(dstv, srcv, edge_attr, row_ptr, deg, al_s1, al_d1, C1,
                                        ed2, wmp, E);
    k_agg1<<<(N + 7) / 8, 256, 0, stream>>>(x, row_ptr, wmp, al_s1, al_d1, lE1, W1, b1, out1b,
                                            N);
    k_stats_bf<32><<<256, 256, 0, stream>>>(out1b, statsA, N);
    k_gemm2_mfma<<<(N + 63) / 64, 256, 0, stream>>>(out1b, statsA, gn1_w, gn1_b, gn1_ms, Bfrag,
                                                    as2, ad2, h2b, al_s2, al_d2, N);
    k_fill2<<<ebl, 256, 0, stream>>>(ed2, al_s2, al_d2, C2, wm2, E);
    k_agg2<<<(N + 3) / 4, 256, 0, stream>>>(h2b, row_ptr, wm2, al_s2, al_d2, lE2, b2, out2b, N);
    k_stats_bf<16><<<256, 256, 0, stream>>>(out2b, statsB, N);
    k_cls<<<(N + 15) / 16, 256, 0, stream>>>(out2b, statsB, gn2_w, gn2_b, gn2_ms, Wc, bc,
                                             (float*)d_out, N);
}

// Round 7
// 277.033 us; speedup vs baseline: 1.2549x; 1.0099x over previous
//
#include <hip/hip_runtime.h>
#include <math.h>

#define NEG_SLOPE 0.2f
#define GEPS 1e-5f

typedef __attribute__((ext_vector_type(8))) short short8;
typedef __attribute__((ext_vector_type(4))) float floatx4;

__device__ __forceinline__ float wave_reduce_sum(float v) {
#pragma unroll
    for (int o = 32; o > 0; o >>= 1) v += __shfl_down(v, o);
    return v;
}

__device__ __forceinline__ ushort f2bf(float f) {
    union { float f; unsigned int i; } c;
    c.f = f;
    unsigned int b = c.i;
    b += 0x7fffu + ((b >> 16) & 1u);
    return (ushort)(b >> 16);
}

__device__ __forceinline__ float bf2f(ushort u) {
    union { unsigned int i; float f; } c;
    c.i = (unsigned int)u << 16;
    return c.f;
}

__device__ __forceinline__ float2 unpack_bf2(unsigned int u) {
    union { unsigned int i; float f; } a, b;
    a.i = u << 16;            // low ushort -> even col
    b.i = u & 0xffff0000u;    // high ushort -> odd col
    return make_float2(a.f, b.f);
}

__device__ __forceinline__ unsigned int pack_bf2(float lo, float hi) {
    return (unsigned int)f2bf(lo) | ((unsigned int)f2bf(hi) << 16);
}

__device__ __forceinline__ float lrelu(float v) {
    return (v > 0.f) ? v : v * NEG_SLOPE;
}

__device__ __forceinline__ float elu_fast(float v) {
    return (v > 0.f) ? v : (__expf(v) - 1.f);
}

// ---------------- merged prologue ----------------
// blocks [0, 16)   : W2 -> bf16 MFMA B-fragment layout
// block  16        : attn consts: C1 (We1.ae1), C2 (We2.ae2), P_s1/P_d1 (W1@as1 / W1@ad1, 3/head)
// blocks [17, 273) : edge_attr column sums + degree histogram
__global__ __launch_bounds__(256) void k_pre(
    const float* __restrict__ W1, const float* __restrict__ as1, const float* __restrict__ ad1,
    const float* __restrict__ ea, const int* __restrict__ dst,
    const float* __restrict__ W2, const float* __restrict__ We1,
    const float* __restrict__ ae1, const float* __restrict__ We2,
    const float* __restrict__ ae2,
    float* __restrict__ ea_sum, int* __restrict__ deg, uint4* __restrict__ Bfrag,
    float* __restrict__ C1, float* __restrict__ C2, float* __restrict__ Ps,
    float* __restrict__ Pd, int E) {
    int b = blockIdx.x;
    if (b < 16) {
        int t = b * 256 + threadIdx.x;  // 4096 threads
        int c = t >> 9, kk = (t >> 6) & 7, L = t & 63;
        int q = L >> 4, n = c * 16 + (L & 15);
        int k0 = kk * 32 + q * 8;
        unsigned int u0 = pack_bf2(W2[(k0 + 0) * 128 + n], W2[(k0 + 1) * 128 + n]);
        unsigned int u1 = pack_bf2(W2[(k0 + 2) * 128 + n], W2[(k0 + 3) * 128 + n]);
        unsigned int u2 = pack_bf2(W2[(k0 + 4) * 128 + n], W2[(k0 + 5) * 128 + n]);
        unsigned int u3 = pack_bf2(W2[(k0 + 6) * 128 + n], W2[(k0 + 7) * 128 + n]);
        Bfrag[t] = make_uint4(u0, u1, u2, u3);
        return;
    }
    if (b == 16) {
        int t = threadIdx.x, h = t >> 6, lane = t & 63;
        float p0 = We1[t] * ae1[t];
        float p1 = We1[256 + t] * ae1[t];
        p0 = wave_reduce_sum(p0);
        p1 = wave_reduce_sum(p1);
        if (lane == 0) { C1[h] = p0; C1[4 + h] = p1; }
        float av = as1[t], dv = ad1[t];
#pragma unroll
        for (int k = 0; k < 3; ++k) {
            float wv = W1[k * 256 + t];
            float ps = wave_reduce_sum(wv * av);
            float pd = wave_reduce_sum(wv * dv);
            if (lane == 0) { Ps[h * 3 + k] = ps; Pd[h * 3 + k] = pd; }
        }
        if (t < 128) {
            float q0 = We2[t] * ae2[t];
            float q1 = We2[128 + t] * ae2[t];
            q0 = wave_reduce_sum(q0);
            q1 = wave_reduce_sum(q1);
            if (lane == 0) { C2[h] = q0; C2[2 + h] = q1; }
        }
        return;
    }
    b -= 17;
    const float2* ea2 = (const float2*)ea;
    float s0 = 0.f, s1 = 0.f;
    for (int e = b * 256 + threadIdx.x; e < E; e += 256 * 256) {
        float2 v = ea2[e];
        s0 += v.x; s1 += v.y;
        atomicAdd(&deg[dst[e]], 1);
    }
    s0 = wave_reduce_sum(s0);
    s1 = wave_reduce_sum(s1);
    if ((threadIdx.x & 63) == 0) {
        atomicAdd(&ea_sum[0], s0);
        atomicAdd(&ea_sum[1], s1);
    }
}

// ---------------- CSR row_ptr scan (block-local) ----------------
__global__ void k_scan1(const int* __restrict__ deg, int* __restrict__ row_ptr,
                        int* __restrict__ bsum, int N) {
    __shared__ int tmp[1024];
    int tid = threadIdx.x;
    int i = blockIdx.x * 1024 + tid;
    int v = (i < N) ? deg[i] : 0;
    tmp[tid] = v;
    __syncthreads();
#pragma unroll
    for (int off = 1; off < 1024; off <<= 1) {
        int t = (tid >= off) ? tmp[tid - off] : 0;
        __syncthreads();
        tmp[tid] += t;
        __syncthreads();
    }
    if (i < N) row_ptr[i + 1] = tmp[tid];
    if (tid == 1023) bsum[blockIdx.x] = tmp[1023];
}

// block prefix recomputed per block in one wave (nb1 <= 64), then applied.
// also: lE1/lE2 self-loop consts (needs ea_sum), and al_s1/al_d1 fill (x . P_s/P_d per head).
__global__ void k_scan23(int* __restrict__ row_ptr, const int* __restrict__ bsum,
                         const float* __restrict__ ea_sum, const float* __restrict__ C1,
                         const float* __restrict__ C2, const float* __restrict__ Ps,
                         const float* __restrict__ Pd, const float* __restrict__ x,
                         float* __restrict__ al_s1, float* __restrict__ al_d1,
                         float* __restrict__ lE1, float* __restrict__ lE2, int N, int E) {
    __shared__ int off_s;
    int t = threadIdx.x;
    if (blockIdx.x == 0 && t >= 64 && t < 68) {
        int k = t - 64;
        float m0 = ea_sum[0] / (float)E, m1 = ea_sum[1] / (float)E;
        lE1[k] = m0 * C1[k] + m1 * C1[4 + k];
        if (k < 2) lE2[k] = m0 * C2[k] + m1 * C2[2 + k];
    }
    if (t < 64) {
        int v = (t < blockIdx.x) ? bsum[t] : 0;
#pragma unroll
        for (int o = 32; o > 0; o >>= 1) v += __shfl_xor(v, o);
        if (t == 0) off_s = v;
    }
    __syncthreads();
    int off = off_s;
    int i = blockIdx.x * 1024 + t;
    if (i == 0) row_ptr[0] = 0;
    if (i < N) {
        row_ptr[i + 1] += off;
        float x0 = x[3 * i], x1 = x[3 * i + 1], x2 = x[3 * i + 2];
        float4 sv, dv;
        sv.x = fmaf(x0, Ps[0], fmaf(x1, Ps[1], x2 * Ps[2]));
        sv.y = fmaf(x0, Ps[3], fmaf(x1, Ps[4], x2 * Ps[5]));
        sv.z = fmaf(x0, Ps[6], fmaf(x1, Ps[7], x2 * Ps[8]));
        sv.w = fmaf(x0, Ps[9], fmaf(x1, Ps[10], x2 * Ps[11]));
        dv.x = fmaf(x0, Pd[0], fmaf(x1, Pd[1], x2 * Pd[2]));
        dv.y = fmaf(x0, Pd[3], fmaf(x1, Pd[4], x2 * Pd[5]));
        dv.z = fmaf(x0, Pd[6], fmaf(x1, Pd[7], x2 * Pd[8]));
        dv.w = fmaf(x0, Pd[9], fmaf(x1, Pd[10], x2 * Pd[11]));
        *(float4*)(al_s1 + 4 * (size_t)i) = sv;
        *(float4*)(al_d1 + 4 * (size_t)i) = dv;
    }
}

// ---------------- CSR scatter fused with layer-1 edge weights ----------------
// writes wmp[slot] = {src, bf16 w0..w3} and ea2[slot] = edge_attr (fp32, for agg2 inline)
__global__ void k_scatfill(const int* __restrict__ dst, const int* __restrict__ src,
                           const float* __restrict__ ea, const int* __restrict__ row_ptr,
                           int* __restrict__ deg, const float* __restrict__ al_s1,
                           const float* __restrict__ al_d1, const float* __restrict__ C1,
                           float2* __restrict__ ea2, uint4* __restrict__ wmp, int E) {
    int e = blockIdx.x * 256 + threadIdx.x;
    if (e >= E) return;
    int d = dst[e];
    int r = atomicSub(&deg[d], 1);
    int slot = row_ptr[d] + r - 1;
    int s = src[e];
    float2 v = ((const float2*)ea)[e];
    float4 as = *(const float4*)(al_s1 + 4 * (size_t)s);
    float4 ad = *(const float4*)(al_d1 + 4 * (size_t)d);
    float w0 = __expf(lrelu(as.x + ad.x + v.x * C1[0] + v.y * C1[4]));
    float w1 = __expf(lrelu(as.y + ad.y + v.x * C1[1] + v.y * C1[5]));
    float w2 = __expf(lrelu(as.z + ad.z + v.x * C1[2] + v.y * C1[6]));
    float w3 = __expf(lrelu(as.w + ad.w + v.x * C1[3] + v.y * C1[7]));
    ea2[slot] = v;
    wmp[slot] = make_uint4((unsigned int)s, pack_bf2(w0, w1), pack_bf2(w2, w3), 0u);
}

// ---------------- layer-1 aggregation in x-space (linearity of W1), ONE-PASS ----------
// z_h = sum_e w_eh * x[src_e] (+ self), out[n] = (z_h . W1col)/dsum_h + b1. 12B gathers.
// block = 8 nodes x 32 lanes. Reduce-scatter: 24 shuffles/node (not 80).
__global__ __launch_bounds__(256) void k_agg1(const float* __restrict__ x,
                                              const int* __restrict__ row_ptr,
                                              const uint4* __restrict__ wmp,
                                              const float* __restrict__ al_s,
                                              const float* __restrict__ al_d,
                                              const float* __restrict__ lE,
                                              const float* __restrict__ W1,
                                              const float* __restrict__ bias,
                                              ushort* __restrict__ out, int N) {
    int l = threadIdx.x & 31;
    int grp = threadIdx.x >> 5;
    int n = blockIdx.x * 8 + grp;
    if (n >= N) return;
    int c0 = l * 8;
    int hh = l >> 3;  // head of owned columns
    // reg-resident W1 columns + bias for the 8 owned cols
    float4 wa0 = *(const float4*)(W1 + c0);
    float4 wa1 = *(const float4*)(W1 + c0 + 4);
    float4 wb0 = *(const float4*)(W1 + 256 + c0);
    float4 wb1 = *(const float4*)(W1 + 256 + c0 + 4);
    float4 wc0 = *(const float4*)(W1 + 512 + c0);
    float4 wc1 = *(const float4*)(W1 + 512 + c0 + 4);
    float4 bv0 = *(const float4*)(bias + c0);
    float4 bv1 = *(const float4*)(bias + c0 + 4);
    float4 asn = *(const float4*)(al_s + 4 * (size_t)n);
    float4 adn = *(const float4*)(al_d + 4 * (size_t)n);
    float ws0 = __expf(lrelu(asn.x + adn.x + lE[0]));
    float ws1 = __expf(lrelu(asn.y + adn.y + lE[1]));
    float ws2 = __expf(lrelu(asn.z + adn.z + lE[2]));
    float ws3 = __expf(lrelu(asn.w + adn.w + lE[3]));
    float z[12];
    float ds[4];
#pragma unroll
    for (int k = 0; k < 12; ++k) z[k] = 0.f;
#pragma unroll
    for (int k = 0; k < 4; ++k) ds[k] = 0.f;
    int i0 = row_ptr[n];
    int cnt = row_ptr[n + 1] - i0;
    for (int j = l; j < cnt; j += 32) {
        uint4 me = wmp[i0 + j];
        int s = (int)me.x;
        float xs0 = x[3 * s], xs1 = x[3 * s + 1], xs2 = x[3 * s + 2];
        float2 w01 = unpack_bf2(me.y);
        float2 w23 = unpack_bf2(me.z);
        z[0] = fmaf(w01.x, xs0, z[0]); z[1] = fmaf(w01.x, xs1, z[1]); z[2] = fmaf(w01.x, xs2, z[2]);
        z[3] = fmaf(w01.y, xs0, z[3]); z[4] = fmaf(w01.y, xs1, z[4]); z[5] = fmaf(w01.y, xs2, z[5]);
        z[6] = fmaf(w23.x, xs0, z[6]); z[7] = fmaf(w23.x, xs1, z[7]); z[8] = fmaf(w23.x, xs2, z[8]);
        z[9] = fmaf(w23.y, xs0, z[9]); z[10] = fmaf(w23.y, xs1, z[10]); z[11] = fmaf(w23.y, xs2, z[11]);
        ds[0] += w01.x; ds[1] += w01.y; ds[2] += w23.x; ds[3] += w23.y;
    }
    // reduce-scatter stage 1 (xor 16): lo lanes keep heads {0,1}, hi lanes heads {2,3}
    bool hi16 = (l & 16) != 0;
    float a0, a1, a2, a3, a4, a5, a6, a7, gv, rv;
    gv = hi16 ? z[0] : z[6];  rv = __shfl_xor(gv, 16); a0 = (hi16 ? z[6] : z[0]) + rv;
    gv = hi16 ? z[1] : z[7];  rv = __shfl_xor(gv, 16); a1 = (hi16 ? z[7] : z[1]) + rv;
    gv = hi16 ? z[2] : z[8];  rv = __shfl_xor(gv, 16); a2 = (hi16 ? z[8] : z[2]) + rv;
    gv = hi16 ? z[3] : z[9];  rv = __shfl_xor(gv, 16); a3 = (hi16 ? z[9] : z[3]) + rv;
    gv = hi16 ? z[4] : z[10]; rv = __shfl_xor(gv, 16); a4 = (hi16 ? z[10] : z[4]) + rv;
    gv = hi16 ? z[5] : z[11]; rv = __shfl_xor(gv, 16); a5 = (hi16 ? z[11] : z[5]) + rv;
    gv = hi16 ? ds[0] : ds[2]; rv = __shfl_xor(gv, 16); a6 = (hi16 ? ds[2] : ds[0]) + rv;
    gv = hi16 ? ds[1] : ds[3]; rv = __shfl_xor(gv, 16); a7 = (hi16 ? ds[3] : ds[1]) + rv;
    // stage 2 (xor 8): keep own head (a0..a2 = headA z, a3..a5 = headB z, a6/a7 = dsA/dsB)
    bool hi8 = (l & 8) != 0;
    float c0v, c1v, c2v, c3v;
    gv = hi8 ? a0 : a3; rv = __shfl_xor(gv, 8); c0v = (hi8 ? a3 : a0) + rv;
    gv = hi8 ? a1 : a4; rv = __shfl_xor(gv, 8); c1v = (hi8 ? a4 : a1) + rv;
    gv = hi8 ? a2 : a5; rv = __shfl_xor(gv, 8); c2v = (hi8 ? a5 : a2) + rv;
    gv = hi8 ? a6 : a7; rv = __shfl_xor(gv, 8); c3v = (hi8 ? a7 : a6) + rv;
    // stages 3-5: full butterfly within the 8-lane head group
#pragma unroll
    for (int o = 4; o > 0; o >>= 1) {
        c0v += __shfl_xor(c0v, o);
        c1v += __shfl_xor(c1v, o);
        c2v += __shfl_xor(c2v, o);
        c3v += __shfl_xor(c3v, o);
    }
    // self-loop contribution for the owned head
    float wsh = (hh == 0) ? ws0 : (hh == 1) ? ws1 : (hh == 2) ? ws2 : ws3;
    float xn0 = x[3 * n], xn1 = x[3 * n + 1], xn2 = x[3 * n + 2];
    c0v = fmaf(wsh, xn0, c0v);
    c1v = fmaf(wsh, xn1, c1v);
    c2v = fmaf(wsh, xn2, c2v);
    c3v += wsh;
    float inv = 1.f / c3v;
    float v0 = fmaf(fmaf(c0v, wa0.x, fmaf(c1v, wb0.x, c2v * wc0.x)), inv, bv0.x);
    float v1 = fmaf(fmaf(c0v, wa0.y, fmaf(c1v, wb0.y, c2v * wc0.y)), inv, bv0.y);
    float v2 = fmaf(fmaf(c0v, wa0.z, fmaf(c1v, wb0.z, c2v * wc0.z)), inv, bv0.z);
    float v3 = fmaf(fmaf(c0v, wa0.w, fmaf(c1v, wb0.w, c2v * wc0.w)), inv, bv0.w);
    float v4 = fmaf(fmaf(c0v, wa1.x, fmaf(c1v, wb1.x, c2v * wc1.x)), inv, bv1.x);
    float v5 = fmaf(fmaf(c0v, wa1.y, fmaf(c1v, wb1.y, c2v * wc1.y)), inv, bv1.y);
    float v6 = fmaf(fmaf(c0v, wa1.z, fmaf(c1v, wb1.z, c2v * wc1.z)), inv, bv1.z);
    float v7 = fmaf(fmaf(c0v, wa1.w, fmaf(c1v, wb1.w, c2v * wc1.w)), inv, bv1.w);
    uint4 o;
    o.x = pack_bf2(v0, v1);
    o.y = pack_bf2(v2, v3);
    o.z = pack_bf2(v4, v5);
    o.w = pack_bf2(v6, v7);
    ((uint4*)out)[(size_t)n * 32 + l] = o;
}

// ---------------- layer-2 aggregation: inline weights in the 4-deep pipeline ----------
// per edge leg: meta {wmp, ea2} -> {al_s2[src] || h2[src]} (parallel, both 3 iters ahead)
// -> exp(lrelu) at consume time. No wm2 array, no fill2 pass.
__global__ __launch_bounds__(256) void k_agg2(const ushort* __restrict__ h2,
                                              const int* __restrict__ row_ptr,
                                              const uint4* __restrict__ wmp,
                                              const float2* __restrict__ ea2,
                                              const float* __restrict__ al_s,
                                              const float* __restrict__ al_d,
                                              const float* __restrict__ C2,
                                              const float* __restrict__ lE,
                                              const float* __restrict__ bias,
                                              ushort* __restrict__ out, int N) {
    int n = blockIdx.x * 4 + (threadIdx.x >> 6);
    if (n >= N) return;
    int lane = threadIdx.x & 63;
    int g = lane >> 4, c16 = lane & 15;
    bool hi = c16 >= 8;
    const uint4* h2u4 = (const uint4*)h2;
    float2 ad = *(const float2*)(al_d + 2 * (size_t)n);
    float2 as = *(const float2*)(al_s + 2 * (size_t)n);
    float wsA = __expf(lrelu(as.x + ad.x + lE[0]));
    float wsB = __expf(lrelu(as.y + ad.y + lE[1]));
    // per-lane head constants for inline weights
    float c2x = hi ? C2[1] : C2[0];
    float c2y = hi ? C2[3] : C2[2];
    float adh = hi ? ad.y : ad.x;
    uint4 hs = h2u4[(size_t)n * 16 + c16];
    float wself = (g == 0) ? (hi ? wsB : wsA) : 0.f;
    float dsum = wself;
    float acc[8];
    {
        float2 t0 = unpack_bf2(hs.x), t1 = unpack_bf2(hs.y);
        float2 t2 = unpack_bf2(hs.z), t3 = unpack_bf2(hs.w);
        acc[0] = wself * t0.x; acc[1] = wself * t0.y;
        acc[2] = wself * t1.x; acc[3] = wself * t1.y;
        acc[4] = wself * t2.x; acc[5] = wself * t2.y;
        acc[6] = wself * t3.x; acc[7] = wself * t3.y;
    }
    int i0 = row_ptr[n];
    int cnt = row_ptr[n + 1] - i0;
    if (cnt > 0) {
        int last = cnt - 1;
        int nit = (cnt + 3) >> 2;
        int j0 = g;      float mkA = 1.f; if (j0 > last) { j0 = last; mkA = 0.f; }
        int j1 = 4 + g;  float mkB = 1.f; if (j1 > last) { j1 = last; mkB = 0.f; }
        int j2 = 8 + g;  float mkC = 1.f; if (j2 > last) { j2 = last; mkC = 0.f; }
        int j3 = 12 + g; float mkD = 1.f; if (j3 > last) { j3 = last; mkD = 0.f; }
        uint4 meA = wmp[i0 + j0]; float2 eaA = ea2[i0 + j0];
        uint4 meB = wmp[i0 + j1]; float2 eaB = ea2[i0 + j1];
        uint4 meC = wmp[i0 + j2]; float2 eaC = ea2[i0 + j2];
        uint4 meD = wmp[i0 + j3]; float2 eaD = ea2[i0 + j3];
        float2 alA = *(const float2*)(al_s + 2 * (size_t)meA.x);
        uint4 gvA = h2u4[(size_t)meA.x * 16 + c16];
        float2 alB = *(const float2*)(al_s + 2 * (size_t)meB.x);
        uint4 gvB = h2u4[(size_t)meB.x * 16 + c16];
        float2 alC = *(const float2*)(al_s + 2 * (size_t)meC.x);
        uint4 gvC = h2u4[(size_t)meC.x * 16 + c16];
        for (int it = 0; it < nit - 1; ++it) {
            float2 alD = *(const float2*)(al_s + 2 * (size_t)meD.x);
            uint4 gvD = h2u4[(size_t)meD.x * 16 + c16];
            int jn = 4 * (it + 4) + g;
            float mn = 1.f;
            if (jn > last) { jn = last; mn = 0.f; }
            uint4 meE = wmp[i0 + jn]; float2 eaE = ea2[i0 + jn];
            float lg = (hi ? alA.y : alA.x) + adh + eaA.x * c2x + eaA.y * c2y;
            float wg = __expf(lrelu(lg)) * mkA;
            dsum += wg;
            float2 u;
            u = unpack_bf2(gvA.x); acc[0] = fmaf(wg, u.x, acc[0]); acc[1] = fmaf(wg, u.y, acc[1]);
            u = unpack_bf2(gvA.y); acc[2] = fmaf(wg, u.x, acc[2]); acc[3] = fmaf(wg, u.y, acc[3]);
            u = unpack_bf2(gvA.z); acc[4] = fmaf(wg, u.x, acc[4]); acc[5] = fmaf(wg, u.y, acc[5]);
            u = unpack_bf2(gvA.w); acc[6] = fmaf(wg, u.x, acc[6]); acc[7] = fmaf(wg, u.y, acc[7]);
            meA = meB; meB = meC; meC = meD; meD = meE;
            eaA = eaB; eaB = eaC; eaC = eaD; eaD = eaE;
            alA = alB; alB = alC; alC = alD;
            gvA = gvB; gvB = gvC; gvC = gvD;
            mkA = mkB; mkB = mkC; mkC = mkD; mkD = mn;
        }
        float lg = (hi ? alA.y : alA.x) + adh + eaA.x * c2x + eaA.y * c2y;
        float wg = __expf(lrelu(lg)) * mkA;
        dsum += wg;
        float2 u;
        u = unpack_bf2(gvA.x); acc[0] = fmaf(wg, u.x, acc[0]); acc[1] = fmaf(wg, u.y, acc[1]);
        u = unpack_bf2(gvA.y); acc[2] = fmaf(wg, u.x, acc[2]); acc[3] = fmaf(wg, u.y, acc[3]);
        u = unpack_bf2(gvA.z); acc[4] = fmaf(wg, u.x, acc[4]); acc[5] = fmaf(wg, u.y, acc[5]);
        u = unpack_bf2(gvA.w); acc[6] = fmaf(wg, u.x, acc[6]); acc[7] = fmaf(wg, u.y, acc[7]);
    }
#pragma unroll
    for (int k = 0; k < 8; ++k) {
        acc[k] += __shfl_xor(acc[k], 16);
        acc[k] += __shfl_xor(acc[k], 32);
    }
    dsum += __shfl_xor(dsum, 16);
    dsum += __shfl_xor(dsum, 32);
    if (g == 0) {
        float inv = 1.f / dsum;
        const float* bp = bias + c16 * 8;
        float4 b0 = *(const float4*)bp;
        float4 b1 = *(const float4*)(bp + 4);
        uint4 o;
        o.x = pack_bf2(fmaf(acc[0], inv, b0.x), fmaf(acc[1], inv, b0.y));
        o.y = pack_bf2(fmaf(acc[2], inv, b0.z), fmaf(acc[3], inv, b0.w));
        o.z = pack_bf2(fmaf(acc[4], inv, b1.x), fmaf(acc[5], inv, b1.y));
        o.w = pack_bf2(fmaf(acc[6], inv, b1.z), fmaf(acc[7], inv, b1.w));
        ((uint4*)out)[(size_t)n * 16 + c16] = o;
    }
}

// ---------------- GraphNorm column stats: uint4 streaming + LDS tree + few atomics ----------
template <int C4>
__global__ __launch_bounds__(256) void k_stats_bf(const ushort* __restrict__ x,
                                                  float* __restrict__ stats, int rows) {
    const int C = C4 * 8;
    const int RG = 256 / C4;
    int t = threadIdx.x;
    int c = t & (C4 - 1);
    int rg = t / C4;
    int rpb = (rows + gridDim.x - 1) / gridDim.x;
    int r0 = blockIdx.x * rpb;
    int r1 = r0 + rpb;
    if (r1 > rows) r1 = rows;
    const uint4* xu = (const uint4*)x;
    float s[8] = {0.f, 0.f, 0.f, 0.f, 0.f, 0.f, 0.f, 0.f};
    float q[8] = {0.f, 0.f, 0.f, 0.f, 0.f, 0.f, 0.f, 0.f};
    for (int r = r0 + rg; r < r1; r += RG) {
        uint4 v = xu[(size_t)r * C4 + c];
        float2 a0 = unpack_bf2(v.x), a1 = unpack_bf2(v.y);
        float2 a2 = unpack_bf2(v.z), a3 = unpack_bf2(v.w);
        s[0] += a0.x; q[0] = fmaf(a0.x, a0.x, q[0]);
        s[1] += a0.y; q[1] = fmaf(a0.y, a0.y, q[1]);
        s[2] += a1.x; q[2] = fmaf(a1.x, a1.x, q[2]);
        s[3] += a1.y; q[3] = fmaf(a1.y, a1.y, q[3]);
        s[4] += a2.x; q[4] = fmaf(a2.x, a2.x, q[4]);
        s[5] += a2.y; q[5] = fmaf(a2.y, a2.y, q[5]);
        s[6] += a3.x; q[6] = fmaf(a3.x, a3.x, q[6]);
        s[7] += a3.y; q[7] = fmaf(a3.y, a3.y, q[7]);
    }
    __shared__ float ls[256 * 16];
#pragma unroll
    for (int k = 0; k < 8; ++k) {
        ls[t * 16 + k] = s[k];
        ls[t * 16 + 8 + k] = q[k];
    }
    __syncthreads();
    if (t < C) {
        int cc = t >> 3, k = t & 7;
        float ssum = 0.f, qsum = 0.f;
#pragma unroll
        for (int g = 0; g < RG; ++g) {
            ssum += ls[(g * C4 + cc) * 16 + k];
            qsum += ls[(g * C4 + cc) * 16 + 8 + k];
        }
        atomicAdd(&stats[t], ssum);
        atomicAdd(&stats[C + t], qsum);
    }
}

// ---------------- MFMA GEMM2 + per-block coef from stats + fused layer-2 attn dots ----------
__global__ __launch_bounds__(256) void k_gemm2_mfma(const ushort* __restrict__ X,
                                                    const float* __restrict__ stats,
                                                    const float* __restrict__ gw,
                                                    const float* __restrict__ gb,
                                                    const float* __restrict__ gms,
                                                    const uint4* __restrict__ Bfrag,
                                                    const float* __restrict__ as2,
                                                    const float* __restrict__ ad2,
                                                    ushort* __restrict__ H2,
                                                    float* __restrict__ al_s,
                                                    float* __restrict__ al_d, int Nn) {
    __shared__ __align__(16) float ABs[512];
    {
        int t = threadIdx.x;
        float inv = 1.f / (float)Nn;
        float mean = stats[t] * inv;
        float cm = mean * gms[t];
        float var = stats[256 + t] * inv - 2.f * cm * mean + cm * cm;
        float A = gw[t] * rsqrtf(var + GEPS);
        ABs[t] = A;
        ABs[256 + t] = gb[t] - A * cm;
    }
    __syncthreads();
    int wave = threadIdx.x >> 6, lane = threadIdx.x & 63;
    int q = lane >> 4, m = lane & 15;
    int rowbase = blockIdx.x * 64 + wave * 16;
    int row = rowbase + m;
    bool valid = row < Nn;
    const uint4* xr4 = (const uint4*)((const unsigned int*)X + (size_t)row * 128);
    uint4 xa[8];
#pragma unroll
    for (int kk = 0; kk < 8; ++kk) {
        int k0 = kk * 32 + q * 8;
        xa[kk] = valid ? xr4[k0 >> 3] : make_uint4(0, 0, 0, 0);
    }
    union { short8 s; unsigned int u[4]; } af[8];
#pragma unroll
    for (int kk = 0; kk < 8; ++kk) {
        int k0 = kk * 32 + q * 8;
        float2 x01 = unpack_bf2(xa[kk].x);
        float2 x23 = unpack_bf2(xa[kk].y);
        float2 x45 = unpack_bf2(xa[kk].z);
        float2 x67 = unpack_bf2(xa[kk].w);
        float4 a0 = *(const float4*)(ABs + k0);
        float4 a1 = *(const float4*)(ABs + k0 + 4);
        float4 b0 = *(const float4*)(ABs + 256 + k0);
        float4 b1 = *(const float4*)(ABs + 256 + k0 + 4);
        float v0 = elu_fast(fmaf(a0.x, x01.x, b0.x));
        float v1 = elu_fast(fmaf(a0.y, x01.y, b0.y));
        float v2 = elu_fast(fmaf(a0.z, x23.x, b0.z));
        float v3 = elu_fast(fmaf(a0.w, x23.y, b0.w));
        float v4 = elu_fast(fmaf(a1.x, x45.x, b1.x));
        float v5 = elu_fast(fmaf(a1.y, x45.y, b1.y));
        float v6 = elu_fast(fmaf(a1.z, x67.x, b1.z));
        float v7 = elu_fast(fmaf(a1.w, x67.y, b1.w));
        af[kk].u[0] = pack_bf2(v0, v1);
        af[kk].u[1] = pack_bf2(v2, v3);
        af[kk].u[2] = pack_bf2(v4, v5);
        af[kk].u[3] = pack_bf2(v6, v7);
    }
    floatx4 acc[8];
#pragma unroll
    for (int c = 0; c < 8; ++c) acc[c] = (floatx4){0.f, 0.f, 0.f, 0.f};
#pragma unroll
    for (int kk = 0; kk < 8; ++kk) {
        const uint4* bpf = Bfrag + kk * 64 + lane;
#pragma unroll
        for (int c = 0; c < 8; ++c) {
            union { short8 s; uint4 u; } bf;
            bf.u = bpf[c * 8 * 64];
            acc[c] = __builtin_amdgcn_mfma_f32_16x16x32_bf16(af[kk].s, bf.s, acc[c], 0, 0, 0);
        }
    }
    float a_s[8], a_d[8];
#pragma unroll
    for (int c = 0; c < 8; ++c) {
        a_s[c] = as2[c * 16 + m];
        a_d[c] = ad2[c * 16 + m];
    }
#pragma unroll
    for (int r = 0; r < 4; ++r) {
        int orow = rowbase + q * 4 + r;
        bool vr = orow < Nn;
        ushort us[8];
        float s0 = 0.f, s1 = 0.f, d0 = 0.f, d1 = 0.f;
#pragma unroll
        for (int c = 0; c < 8; ++c) {
            us[c] = f2bf(acc[c][r]);
            float v = bf2f(us[c]);
            if (c < 4) {
                s0 = fmaf(v, a_s[c], s0);
                d0 = fmaf(v, a_d[c], d0);
            } else {
                s1 = fmaf(v, a_s[c], s1);
                d1 = fmaf(v, a_d[c], d1);
            }
        }
#pragma unroll
        for (int o = 1; o < 16; o <<= 1) {
            s0 += __shfl_xor(s0, o);
            s1 += __shfl_xor(s1, o);
            d0 += __shfl_xor(d0, o);
            d1 += __shfl_xor(d1, o);
        }
        if (vr) {
            ushort* op = H2 + (size_t)orow * 128 + m;
#pragma unroll
            for (int c = 0; c < 8; ++c) op[c * 16] = us[c];
            if (m == 0) {
                *(float2*)(al_s + 2 * (size_t)orow) = make_float2(s0, s1);
                *(float2*)(al_d + 2 * (size_t)orow) = make_float2(d0, d1);
            }
        }
    }
}

// ---------------- classifier: per-block coef from stats + fused GraphNorm+ELU ----------------
__global__ __launch_bounds__(256) void k_cls(const ushort* __restrict__ X,
                                             const float* __restrict__ stats,
                                             const float* __restrict__ gw,
                                             const float* __restrict__ gb,
                                             const float* __restrict__ gms,
                                             const float* __restrict__ Wc,
                                             const float* __restrict__ bc,
                                             float* __restrict__ out, int Nn) {
    __shared__ __align__(16) float ls[16 * 132];
    __shared__ __align__(16) float wT[13 * 132];
    __shared__ __align__(16) float ABs[256];
    __shared__ float bS[13];
    int t = threadIdx.x;
    int n0 = blockIdx.x * 16;
    if (t < 128) {
        float inv = 1.f / (float)Nn;
        float mean = stats[t] * inv;
        float cm = mean * gms[t];
        float var = stats[128 + t] * inv - 2.f * cm * mean + cm * cm;
        float A = gw[t] * rsqrtf(var + GEPS);
        ABs[t] = A;
        ABs[128 + t] = gb[t] - A * cm;
    }
    for (int i = t; i < 128 * 13; i += 256) {
        int k = i / 13, j = i - k * 13;
        wT[j * 132 + k] = Wc[i];
    }
    if (t < 13) bS[t] = bc[t];
    __syncthreads();
    const unsigned int* xu = (const unsigned int*)X;
    for (int idx = t; idx < 16 * 64; idx += 256) {
        int r = idx >> 6, ku = idx & 63;
        int row = n0 + r;
        float vx = 0.f, vy = 0.f;
        if (row < Nn) {
            float2 v = unpack_bf2(xu[(size_t)row * 64 + ku]);
            int k = 2 * ku;
            vx = elu_fast(fmaf(ABs[k], v.x, ABs[128 + k]));
            vy = elu_fast(fmaf(ABs[k + 1], v.y, ABs[128 + k + 1]));
        }
        ls[r * 132 + 2 * ku] = vx;
        ls[r * 132 + 2 * ku + 1] = vy;
    }
    __syncthreads();
    if (t < 208) {
        int r = t / 13, j = t - r * 13;
        int row = n0 + r;
        if (row < Nn) {
            float acc = bS[j];
            const float* lr = &ls[r * 132];
            const float* wr = &wT[j * 132];
#pragma unroll 8
            for (int k = 0; k < 128; k += 4) {
                float4 a = *(const float4*)&lr[k];
                float4 b = *(const float4*)&wr[k];
                acc = fmaf(a.x, b.x, fmaf(a.y, b.y, fmaf(a.z, b.z, fmaf(a.w, b.w, acc))));
            }
            out[(size_t)row * 13 + j] = acc;
        }
    }
}

extern "C" void kernel_launch(void* const* d_in, const int* in_sizes, int n_in, void* d_out,
                              int out_size, void* d_ws, size_t ws_size, hipStream_t stream) {
    const float* x = (const float*)d_in[0];
    const int* edge_index = (const int*)d_in[1];
    const float* edge_attr = (const float*)d_in[2];
    const float* W1 = (const float*)d_in[3];
    const float* We1 = (const float*)d_in[4];
    const float* as1 = (const float*)d_in[5];
    const float* ad1 = (const float*)d_in[6];
    const float* ae1 = (const float*)d_in[7];
    const float* b1 = (const float*)d_in[8];
    const float* gn1_w = (const float*)d_in[9];
    const float* gn1_b = (const float*)d_in[10];
    const float* gn1_ms = (const float*)d_in[11];
    const float* W2 = (const float*)d_in[12];
    const float* We2 = (const float*)d_in[13];
    const float* as2 = (const float*)d_in[14];
    const float* ad2 = (const float*)d_in[15];
    const float* ae2 = (const float*)d_in[16];
    const float* b2 = (const float*)d_in[17];
    const float* gn2_w = (const float*)d_in[18];
    const float* gn2_b = (const float*)d_in[19];
    const float* gn2_ms = (const float*)d_in[20];
    const float* Wc = (const float*)d_in[21];
    const float* bc = (const float*)d_in[22];

    const int N = in_sizes[0] / 3;
    const int E = in_sizes[1] / 2;
    const int* srcv = edge_index;
    const int* dstv = edge_index + E;

    // ---- workspace carve (256B-aligned, byte-based) ----
    char* w = (char*)d_ws;
    auto carveB = [&](size_t bytes) -> void* {
        void* p = (void*)w;
        w += ((bytes + 255) / 256) * 256;
        return p;
    };
    // zeroed region first:
    int* deg = (int*)carveB((size_t)N * 4);
    float* ea_sum = (float*)carveB(8);
    float* statsA = (float*)carveB(512 * 4);
    float* statsB = (float*)carveB(256 * 4);
    char* zero_end = w;
    // not zeroed:
    int* row_ptr = (int*)carveB((size_t)(N + 1) * 4);
    int* bsum = (int*)carveB(1024 * 4);
    float2* ea2 = (float2*)carveB((size_t)E * 8);
    uint4* wmp = (uint4*)carveB((size_t)E * 16);
    float* C1 = (float*)carveB(8 * 4);
    float* C2 = (float*)carveB(4 * 4);
    float* Ps = (float*)carveB(12 * 4);
    float* Pd = (float*)carveB(12 * 4);
    float* lE1 = (float*)carveB(4 * 4);
    float* lE2 = (float*)carveB(2 * 4);
    uint4* Bfrag = (uint4*)carveB(4096 * 16);
    float* al_s1 = (float*)carveB((size_t)N * 4 * 4);
    float* al_d1 = (float*)carveB((size_t)N * 4 * 4);
    float* al_s2 = (float*)carveB((size_t)N * 2 * 4);
    float* al_d2 = (float*)carveB((size_t)N * 2 * 4);
    ushort* h2b = (ushort*)carveB((size_t)N * 128 * 2);   // bf16 h2
    ushort* out1b = (ushort*)carveB((size_t)N * 256 * 2); // bf16 layer-1 output
    ushort* out2b = (ushort*)carveB((size_t)N * 128 * 2); // bf16 layer-2 output

    hipMemsetAsync(deg, 0, (size_t)(zero_end - (char*)deg), stream);

    const int nb1 = (N + 1023) / 1024;
    const int ebl = (E + 255) / 256;

    k_pre<<<17 + 256, 256, 0, stream>>>(W1, as1, ad1, edge_attr, dstv, W2, We1, ae1, We2, ae2,
                                        ea_sum, deg, Bfrag, C1, C2, Ps, Pd, E);
    k_scan1<<<nb1, 1024, 0, stream>>>(deg, row_ptr, bsum, N);
    k_scan23<<<nb1, 1024, 0, stream>>>(row_ptr, bsum, ea_sum, C1, C2, Ps, Pd, x, al_s1, al_d1,
                                       lE1, lE2, N, E);
    k_scatfill<<<ebl, 256, 0, stream>>>(dstv, srcv, edge_attr, row_ptr, deg, al_s1, al_d1, C1,
                                        ea2, wmp, E);
    k_agg1<<<(N + 7) / 8, 256, 0, stream>>>(x, row_ptr, wmp, al_s1, al_d1, lE1, W1, b1, out1b,
                                            N);
    k_stats_bf<32><<<256, 256, 0, stream>>>(out1b, statsA, N);
    k_gemm2_mfma<<<(N + 63) / 64, 256, 0, stream>>>(out1b, statsA, gn1_w, gn1_b, gn1_ms, Bfrag,
                                                    as2, ad2, h2b, al_s2, al_d2, N);
    k_agg2<<<(N + 3) / 4, 256, 0, stream>>>(h2b, row_ptr, wmp, ea2, al_s2, al_d2, C2, lE2, b2,
                                            out2b, N);
    k_stats_bf<16><<<256, 256, 0, stream>>>(out2b, statsB, N);
    k_cls<<<(N + 15) / 16, 256, 0, stream>>>(out2b, statsB, gn2_w, gn2_b, gn2_ms, Wc, bc,
                                             (float*)d_out, N);
}

// Round 8
// 265.768 us; speedup vs baseline: 1.3081x; 1.0424x over previous
//
#include <hip/hip_runtime.h>
#include <math.h>

#define NEG_SLOPE 0.2f
#define GEPS 1e-5f

typedef __attribute__((ext_vector_type(8))) short short8;
typedef __attribute__((ext_vector_type(4))) float floatx4;

__device__ __forceinline__ float wave_reduce_sum(float v) {
#pragma unroll
    for (int o = 32; o > 0; o >>= 1) v += __shfl_down(v, o);
    return v;
}

__device__ __forceinline__ ushort f2bf(float f) {
    union { float f; unsigned int i; } c;
    c.f = f;
    unsigned int b = c.i;
    b += 0x7fffu + ((b >> 16) & 1u);
    return (ushort)(b >> 16);
}

__device__ __forceinline__ float bf2f(ushort u) {
    union { unsigned int i; float f; } c;
    c.i = (unsigned int)u << 16;
    return c.f;
}

__device__ __forceinline__ float2 unpack_bf2(unsigned int u) {
    union { unsigned int i; float f; } a, b;
    a.i = u << 16;            // low ushort -> even col
    b.i = u & 0xffff0000u;    // high ushort -> odd col
    return make_float2(a.f, b.f);
}

__device__ __forceinline__ unsigned int pack_bf2(float lo, float hi) {
    return (unsigned int)f2bf(lo) | ((unsigned int)f2bf(hi) << 16);
}

__device__ __forceinline__ float lrelu(float v) {
    return (v > 0.f) ? v : v * NEG_SLOPE;
}

__device__ __forceinline__ float elu_fast(float v) {
    return (v > 0.f) ? v : (__expf(v) - 1.f);
}

// ---------------- merged prologue ----------------
// blocks [0, 16)   : W2 -> bf16 MFMA B-fragment layout
// block  16        : attn consts: C1 (We1.ae1), C2 (We2.ae2), P_s1/P_d1 (W1@as1 / W1@ad1, 3/head)
// blocks [17, 273) : edge_attr column sums + degree histogram
__global__ __launch_bounds__(256) void k_pre(
    const float* __restrict__ W1, const float* __restrict__ as1, const float* __restrict__ ad1,
    const float* __restrict__ ea, const int* __restrict__ dst,
    const float* __restrict__ W2, const float* __restrict__ We1,
    const float* __restrict__ ae1, const float* __restrict__ We2,
    const float* __restrict__ ae2,
    float* __restrict__ ea_sum, int* __restrict__ deg, uint4* __restrict__ Bfrag,
    float* __restrict__ C1, float* __restrict__ C2, float* __restrict__ Ps,
    float* __restrict__ Pd, int E) {
    int b = blockIdx.x;
    if (b < 16) {
        int t = b * 256 + threadIdx.x;  // 4096 threads
        int c = t >> 9, kk = (t >> 6) & 7, L = t & 63;
        int q = L >> 4, n = c * 16 + (L & 15);
        int k0 = kk * 32 + q * 8;
        unsigned int u0 = pack_bf2(W2[(k0 + 0) * 128 + n], W2[(k0 + 1) * 128 + n]);
        unsigned int u1 = pack_bf2(W2[(k0 + 2) * 128 + n], W2[(k0 + 3) * 128 + n]);
        unsigned int u2 = pack_bf2(W2[(k0 + 4) * 128 + n], W2[(k0 + 5) * 128 + n]);
        unsigned int u3 = pack_bf2(W2[(k0 + 6) * 128 + n], W2[(k0 + 7) * 128 + n]);
        Bfrag[t] = make_uint4(u0, u1, u2, u3);
        return;
    }
    if (b == 16) {
        int t = threadIdx.x, h = t >> 6, lane = t & 63;
        float p0 = We1[t] * ae1[t];
        float p1 = We1[256 + t] * ae1[t];
        p0 = wave_reduce_sum(p0);
        p1 = wave_reduce_sum(p1);
        if (lane == 0) { C1[h] = p0; C1[4 + h] = p1; }
        float av = as1[t], dv = ad1[t];
#pragma unroll
        for (int k = 0; k < 3; ++k) {
            float wv = W1[k * 256 + t];
            float ps = wave_reduce_sum(wv * av);
            float pd = wave_reduce_sum(wv * dv);
            if (lane == 0) { Ps[h * 3 + k] = ps; Pd[h * 3 + k] = pd; }
        }
        if (t < 128) {
            float q0 = We2[t] * ae2[t];
            float q1 = We2[128 + t] * ae2[t];
            q0 = wave_reduce_sum(q0);
            q1 = wave_reduce_sum(q1);
            if (lane == 0) { C2[h] = q0; C2[2 + h] = q1; }
        }
        return;
    }
    b -= 17;
    const float2* ea2 = (const float2*)ea;
    float s0 = 0.f, s1 = 0.f;
    for (int e = b * 256 + threadIdx.x; e < E; e += 256 * 256) {
        float2 v = ea2[e];
        s0 += v.x; s1 += v.y;
        atomicAdd(&deg[dst[e]], 1);
    }
    s0 = wave_reduce_sum(s0);
    s1 = wave_reduce_sum(s1);
    if ((threadIdx.x & 63) == 0) {
        atomicAdd(&ea_sum[0], s0);
        atomicAdd(&ea_sum[1], s1);
    }
}

// ---------------- CSR row_ptr scan (block-local) ----------------
__global__ void k_scan1(const int* __restrict__ deg, int* __restrict__ row_ptr,
                        int* __restrict__ bsum, int N) {
    __shared__ int tmp[1024];
    int tid = threadIdx.x;
    int i = blockIdx.x * 1024 + tid;
    int v = (i < N) ? deg[i] : 0;
    tmp[tid] = v;
    __syncthreads();
#pragma unroll
    for (int off = 1; off < 1024; off <<= 1) {
        int t = (tid >= off) ? tmp[tid - off] : 0;
        __syncthreads();
        tmp[tid] += t;
        __syncthreads();
    }
    if (i < N) row_ptr[i + 1] = tmp[tid];
    if (tid == 1023) bsum[blockIdx.x] = tmp[1023];
}

// block prefix recomputed per block in one wave (nb1 <= 64), then applied.
// also: lE1/lE2 self-loop consts (needs ea_sum), and al_s1/al_d1 fill (x . P_s/P_d per head).
__global__ void k_scan23(int* __restrict__ row_ptr, const int* __restrict__ bsum,
                         const float* __restrict__ ea_sum, const float* __restrict__ C1,
                         const float* __restrict__ C2, const float* __restrict__ Ps,
                         const float* __restrict__ Pd, const float* __restrict__ x,
                         float* __restrict__ al_s1, float* __restrict__ al_d1,
                         float* __restrict__ lE1, float* __restrict__ lE2, int N, int E) {
    __shared__ int off_s;
    int t = threadIdx.x;
    if (blockIdx.x == 0 && t >= 64 && t < 68) {
        int k = t - 64;
        float m0 = ea_sum[0] / (float)E, m1 = ea_sum[1] / (float)E;
        lE1[k] = m0 * C1[k] + m1 * C1[4 + k];
        if (k < 2) lE2[k] = m0 * C2[k] + m1 * C2[2 + k];
    }
    if (t < 64) {
        int v = (t < blockIdx.x) ? bsum[t] : 0;
#pragma unroll
        for (int o = 32; o > 0; o >>= 1) v += __shfl_xor(v, o);
        if (t == 0) off_s = v;
    }
    __syncthreads();
    int off = off_s;
    int i = blockIdx.x * 1024 + t;
    if (i == 0) row_ptr[0] = 0;
    if (i < N) {
        row_ptr[i + 1] += off;
        float x0 = x[3 * i], x1 = x[3 * i + 1], x2 = x[3 * i + 2];
        float4 sv, dv;
        sv.x = fmaf(x0, Ps[0], fmaf(x1, Ps[1], x2 * Ps[2]));
        sv.y = fmaf(x0, Ps[3], fmaf(x1, Ps[4], x2 * Ps[5]));
        sv.z = fmaf(x0, Ps[6], fmaf(x1, Ps[7], x2 * Ps[8]));
        sv.w = fmaf(x0, Ps[9], fmaf(x1, Ps[10], x2 * Ps[11]));
        dv.x = fmaf(x0, Pd[0], fmaf(x1, Pd[1], x2 * Pd[2]));
        dv.y = fmaf(x0, Pd[3], fmaf(x1, Pd[4], x2 * Pd[5]));
        dv.z = fmaf(x0, Pd[6], fmaf(x1, Pd[7], x2 * Pd[8]));
        dv.w = fmaf(x0, Pd[9], fmaf(x1, Pd[10], x2 * Pd[11]));
        *(float4*)(al_s1 + 4 * (size_t)i) = sv;
        *(float4*)(al_d1 + 4 * (size_t)i) = dv;
    }
}

// ---------------- CSR scatter fused with layer-1 edge weights ----------------
// writes wmp[slot] = {src, bf16 w0..w3} and ea2[slot] = edge_attr (fp32, for agg2 inline)
__global__ void k_scatfill(const int* __restrict__ dst, const int* __restrict__ src,
                           const float* __restrict__ ea, const int* __restrict__ row_ptr,
                           int* __restrict__ deg, const float* __restrict__ al_s1,
                           const float* __restrict__ al_d1, const float* __restrict__ C1,
                           float2* __restrict__ ea2, uint4* __restrict__ wmp, int E) {
    int e = blockIdx.x * 256 + threadIdx.x;
    if (e >= E) return;
    int d = dst[e];
    int r = atomicSub(&deg[d], 1);
    int slot = row_ptr[d] + r - 1;
    int s = src[e];
    float2 v = ((const float2*)ea)[e];
    float4 as = *(const float4*)(al_s1 + 4 * (size_t)s);
    float4 ad = *(const float4*)(al_d1 + 4 * (size_t)d);
    float w0 = __expf(lrelu(as.x + ad.x + v.x * C1[0] + v.y * C1[4]));
    float w1 = __expf(lrelu(as.y + ad.y + v.x * C1[1] + v.y * C1[5]));
    float w2 = __expf(lrelu(as.z + ad.z + v.x * C1[2] + v.y * C1[6]));
    float w3 = __expf(lrelu(as.w + ad.w + v.x * C1[3] + v.y * C1[7]));
    ea2[slot] = v;
    wmp[slot] = make_uint4((unsigned int)s, pack_bf2(w0, w1), pack_bf2(w2, w3), 0u);
}

// ---------------- layer-1 aggregation in x-space, ONE-PASS, u-output ----------
// u_h = (sum_e w_eh x[src_e] + self) / dsum_h  in R^3 per head. out1 never materialized:
// out1[n][c] = u_{n,h(c)} . W1col_c + b1_c is expanded later (k_gemm2) from uarr (48B/node).
__global__ __launch_bounds__(256) void k_agg1(const float* __restrict__ x,
                                              const int* __restrict__ row_ptr,
                                              const uint4* __restrict__ wmp,
                                              const float* __restrict__ al_s,
                                              const float* __restrict__ al_d,
                                              const float* __restrict__ lE,
                                              float4* __restrict__ uarr, int N) {
    int l = threadIdx.x & 31;
    int grp = threadIdx.x >> 5;
    int n = blockIdx.x * 8 + grp;
    if (n >= N) return;
    int hh = l >> 3;  // head owned by this lane
    float4 asn = *(const float4*)(al_s + 4 * (size_t)n);
    float4 adn = *(const float4*)(al_d + 4 * (size_t)n);
    float ws0 = __expf(lrelu(asn.x + adn.x + lE[0]));
    float ws1 = __expf(lrelu(asn.y + adn.y + lE[1]));
    float ws2 = __expf(lrelu(asn.z + adn.z + lE[2]));
    float ws3 = __expf(lrelu(asn.w + adn.w + lE[3]));
    float z[12];
    float ds[4];
#pragma unroll
    for (int k = 0; k < 12; ++k) z[k] = 0.f;
#pragma unroll
    for (int k = 0; k < 4; ++k) ds[k] = 0.f;
    int i0 = row_ptr[n];
    int cnt = row_ptr[n + 1] - i0;
    for (int j = l; j < cnt; j += 32) {
        uint4 me = wmp[i0 + j];
        int s = (int)me.x;
        float xs0 = x[3 * s], xs1 = x[3 * s + 1], xs2 = x[3 * s + 2];
        float2 w01 = unpack_bf2(me.y);
        float2 w23 = unpack_bf2(me.z);
        z[0] = fmaf(w01.x, xs0, z[0]); z[1] = fmaf(w01.x, xs1, z[1]); z[2] = fmaf(w01.x, xs2, z[2]);
        z[3] = fmaf(w01.y, xs0, z[3]); z[4] = fmaf(w01.y, xs1, z[4]); z[5] = fmaf(w01.y, xs2, z[5]);
        z[6] = fmaf(w23.x, xs0, z[6]); z[7] = fmaf(w23.x, xs1, z[7]); z[8] = fmaf(w23.x, xs2, z[8]);
        z[9] = fmaf(w23.y, xs0, z[9]); z[10] = fmaf(w23.y, xs1, z[10]); z[11] = fmaf(w23.y, xs2, z[11]);
        ds[0] += w01.x; ds[1] += w01.y; ds[2] += w23.x; ds[3] += w23.y;
    }
    // reduce-scatter stage 1 (xor 16): lo lanes keep heads {0,1}, hi lanes heads {2,3}
    bool hi16 = (l & 16) != 0;
    float a0, a1, a2, a3, a4, a5, a6, a7, gv, rv;
    gv = hi16 ? z[0] : z[6];  rv = __shfl_xor(gv, 16); a0 = (hi16 ? z[6] : z[0]) + rv;
    gv = hi16 ? z[1] : z[7];  rv = __shfl_xor(gv, 16); a1 = (hi16 ? z[7] : z[1]) + rv;
    gv = hi16 ? z[2] : z[8];  rv = __shfl_xor(gv, 16); a2 = (hi16 ? z[8] : z[2]) + rv;
    gv = hi16 ? z[3] : z[9];  rv = __shfl_xor(gv, 16); a3 = (hi16 ? z[9] : z[3]) + rv;
    gv = hi16 ? z[4] : z[10]; rv = __shfl_xor(gv, 16); a4 = (hi16 ? z[10] : z[4]) + rv;
    gv = hi16 ? z[5] : z[11]; rv = __shfl_xor(gv, 16); a5 = (hi16 ? z[11] : z[5]) + rv;
    gv = hi16 ? ds[0] : ds[2]; rv = __shfl_xor(gv, 16); a6 = (hi16 ? ds[2] : ds[0]) + rv;
    gv = hi16 ? ds[1] : ds[3]; rv = __shfl_xor(gv, 16); a7 = (hi16 ? ds[3] : ds[1]) + rv;
    // stage 2 (xor 8): keep own head
    bool hi8 = (l & 8) != 0;
    float c0v, c1v, c2v, c3v;
    gv = hi8 ? a0 : a3; rv = __shfl_xor(gv, 8); c0v = (hi8 ? a3 : a0) + rv;
    gv = hi8 ? a1 : a4; rv = __shfl_xor(gv, 8); c1v = (hi8 ? a4 : a1) + rv;
    gv = hi8 ? a2 : a5; rv = __shfl_xor(gv, 8); c2v = (hi8 ? a5 : a2) + rv;
    gv = hi8 ? a6 : a7; rv = __shfl_xor(gv, 8); c3v = (hi8 ? a7 : a6) + rv;
    // stages 3-5: full butterfly within the 8-lane head group
#pragma unroll
    for (int o = 4; o > 0; o >>= 1) {
        c0v += __shfl_xor(c0v, o);
        c1v += __shfl_xor(c1v, o);
        c2v += __shfl_xor(c2v, o);
        c3v += __shfl_xor(c3v, o);
    }
    // self-loop for the owned head
    float wsh = (hh == 0) ? ws0 : (hh == 1) ? ws1 : (hh == 2) ? ws2 : ws3;
    float xn0 = x[3 * n], xn1 = x[3 * n + 1], xn2 = x[3 * n + 2];
    c0v = fmaf(wsh, xn0, c0v);
    c1v = fmaf(wsh, xn1, c1v);
    c2v = fmaf(wsh, xn2, c2v);
    c3v += wsh;
    if ((l & 7) == 0) {
        float inv = 1.f / c3v;
        uarr[(size_t)n * 4 + hh] = make_float4(c0v * inv, c1v * inv, c2v * inv, 0.f);
    }
}

// ---------------- per-head moments of u: Su(3) + Suu^T(6) -> 36 floats ----------------
// thread's head is fixed (i = bid*256 + t + k*grid*256, stride % 4 == 0 -> head = t&3).
__global__ __launch_bounds__(256) void k_mom(const float4* __restrict__ uarr,
                                             float* __restrict__ mom, int N4) {
    int t = threadIdx.x;
    float m[9] = {0.f, 0.f, 0.f, 0.f, 0.f, 0.f, 0.f, 0.f, 0.f};
    for (int i = blockIdx.x * 256 + t; i < N4; i += gridDim.x * 256) {
        float4 u = uarr[i];
        m[0] += u.x; m[1] += u.y; m[2] += u.z;
        m[3] = fmaf(u.x, u.x, m[3]);
        m[4] = fmaf(u.y, u.y, m[4]);
        m[5] = fmaf(u.z, u.z, m[5]);
        m[6] = fmaf(u.x, u.y, m[6]);
        m[7] = fmaf(u.x, u.z, m[7]);
        m[8] = fmaf(u.y, u.z, m[8]);
    }
    __shared__ float ls[256 * 9];
#pragma unroll
    for (int k = 0; k < 9; ++k) ls[t * 9 + k] = m[k];
    __syncthreads();
    if (t < 36) {
        int h = t / 9, k = t - h * 9;
        float s = 0.f;
        for (int tt = h; tt < 256; tt += 4) s += ls[tt * 9 + k];
        atomicAdd(&mom[t], s);
    }
}

// ---------------- MFMA GEMM2: expand out1 from uarr + analytic GraphNorm coefs ----------
// out1[r][c] = u_{r,h(c)} . (W1col_c) + b1_c ; norm coefs A,B from per-head moments.
__global__ __launch_bounds__(256) void k_gemm2_mfma(const float4* __restrict__ uarr,
                                                    const float* __restrict__ mom,
                                                    const float* __restrict__ W1,
                                                    const float* __restrict__ b1,
                                                    const float* __restrict__ gw,
                                                    const float* __restrict__ gb,
                                                    const float* __restrict__ gms,
                                                    const uint4* __restrict__ Bfrag,
                                                    const float* __restrict__ as2,
                                                    const float* __restrict__ ad2,
                                                    ushort* __restrict__ H2,
                                                    float* __restrict__ al_s,
                                                    float* __restrict__ al_d, int Nn) {
    __shared__ __align__(16) float4 Wc4[256];   // (w0,w1,w2,b1) per col
    __shared__ __align__(16) float2 ABs2[256];  // (A,B) per col
    __shared__ __align__(16) float4 Uld[256];   // [64 rows][4 heads]
    {
        int t = threadIdx.x;
        float w0 = W1[t], w1 = W1[256 + t], w2 = W1[512 + t], bb = b1[t];
        Wc4[t] = make_float4(w0, w1, w2, bb);
        const float* mh = mom + (t >> 6) * 9;
        float invN = 1.f / (float)Nn;
        float sw = w0 * mh[0] + w1 * mh[1] + w2 * mh[2];
        float mean = fmaf(sw, invN, bb);
        float quad = w0 * w0 * mh[3] + w1 * w1 * mh[4] + w2 * w2 * mh[5] +
                     2.f * (w0 * w1 * mh[6] + w0 * w2 * mh[7] + w1 * w2 * mh[8]);
        float E2 = fmaf(fmaf(2.f * bb, sw, quad), invN, bb * bb);
        float cm = mean * gms[t];
        float var = E2 - 2.f * cm * mean + cm * cm;
        float A = gw[t] * rsqrtf(var + GEPS);
        ABs2[t] = make_float2(A, gb[t] - A * cm);
        int row = blockIdx.x * 64 + (t >> 2);
        Uld[t] = (row < Nn) ? uarr[(size_t)row * 4 + (t & 3)] : make_float4(0.f, 0.f, 0.f, 0.f);
    }
    __syncthreads();
    int wave = threadIdx.x >> 6, lane = threadIdx.x & 63;
    int q = lane >> 4, m = lane & 15;
    int rowbase = blockIdx.x * 64 + wave * 16;
    union { short8 s; unsigned int u[4]; } af[8];
#pragma unroll
    for (int kk = 0; kk < 8; ++kk) {
        float4 u = Uld[(wave * 16 + m) * 4 + (kk >> 1)];
        int c0 = kk * 32 + q * 8;
        float vv[8];
#pragma unroll
        for (int j = 0; j < 8; ++j) {
            float4 wv = Wc4[c0 + j];
            float2 ab = ABs2[c0 + j];
            float X = fmaf(u.x, wv.x, fmaf(u.y, wv.y, fmaf(u.z, wv.z, wv.w)));
            vv[j] = elu_fast(fmaf(ab.x, X, ab.y));
        }
        af[kk].u[0] = pack_bf2(vv[0], vv[1]);
        af[kk].u[1] = pack_bf2(vv[2], vv[3]);
        af[kk].u[2] = pack_bf2(vv[4], vv[5]);
        af[kk].u[3] = pack_bf2(vv[6], vv[7]);
    }
    floatx4 acc[8];
#pragma unroll
    for (int c = 0; c < 8; ++c) acc[c] = (floatx4){0.f, 0.f, 0.f, 0.f};
#pragma unroll
    for (int kk = 0; kk < 8; ++kk) {
        const uint4* bpf = Bfrag + kk * 64 + lane;
#pragma unroll
        for (int c = 0; c < 8; ++c) {
            union { short8 s; uint4 u; } bf;
            bf.u = bpf[c * 8 * 64];
            acc[c] = __builtin_amdgcn_mfma_f32_16x16x32_bf16(af[kk].s, bf.s, acc[c], 0, 0, 0);
        }
    }
    float a_s[8], a_d[8];
#pragma unroll
    for (int c = 0; c < 8; ++c) {
        a_s[c] = as2[c * 16 + m];
        a_d[c] = ad2[c * 16 + m];
    }
#pragma unroll
    for (int r = 0; r < 4; ++r) {
        int orow = rowbase + q * 4 + r;
        bool vr = orow < Nn;
        ushort us[8];
        float s0 = 0.f, s1 = 0.f, d0 = 0.f, d1 = 0.f;
#pragma unroll
        for (int c = 0; c < 8; ++c) {
            us[c] = f2bf(acc[c][r]);
            float v = bf2f(us[c]);
            if (c < 4) {
                s0 = fmaf(v, a_s[c], s0);
                d0 = fmaf(v, a_d[c], d0);
            } else {
                s1 = fmaf(v, a_s[c], s1);
                d1 = fmaf(v, a_d[c], d1);
            }
        }
#pragma unroll
        for (int o = 1; o < 16; o <<= 1) {
            s0 += __shfl_xor(s0, o);
            s1 += __shfl_xor(s1, o);
            d0 += __shfl_xor(d0, o);
            d1 += __shfl_xor(d1, o);
        }
        if (vr) {
            ushort* op = H2 + (size_t)orow * 128 + m;
#pragma unroll
            for (int c = 0; c < 8; ++c) op[c * 16] = us[c];
            if (m == 0) {
                *(float2*)(al_s + 2 * (size_t)orow) = make_float2(s0, s1);
                *(float2*)(al_d + 2 * (size_t)orow) = make_float2(d0, d1);
            }
        }
    }
}

// ---------------- layer-2 aggregation: inline weights in the 4-deep pipeline ----------
__global__ __launch_bounds__(256) void k_agg2(const ushort* __restrict__ h2,
                                              const int* __restrict__ row_ptr,
                                              const uint4* __restrict__ wmp,
                                              const float2* __restrict__ ea2,
                                              const float* __restrict__ al_s,
                                              const float* __restrict__ al_d,
                                              const float* __restrict__ C2,
                                              const float* __restrict__ lE,
                                              const float* __restrict__ bias,
                                              ushort* __restrict__ out, int N) {
    int n = blockIdx.x * 4 + (threadIdx.x >> 6);
    if (n >= N) return;
    int lane = threadIdx.x & 63;
    int g = lane >> 4, c16 = lane & 15;
    bool hi = c16 >= 8;
    const uint4* h2u4 = (const uint4*)h2;
    float2 ad = *(const float2*)(al_d + 2 * (size_t)n);
    float2 as = *(const float2*)(al_s + 2 * (size_t)n);
    float wsA = __expf(lrelu(as.x + ad.x + lE[0]));
    float wsB = __expf(lrelu(as.y + ad.y + lE[1]));
    float c2x = hi ? C2[1] : C2[0];
    float c2y = hi ? C2[3] : C2[2];
    float adh = hi ? ad.y : ad.x;
    uint4 hs = h2u4[(size_t)n * 16 + c16];
    float wself = (g == 0) ? (hi ? wsB : wsA) : 0.f;
    float dsum = wself;
    float acc[8];
    {
        float2 t0 = unpack_bf2(hs.x), t1 = unpack_bf2(hs.y);
        float2 t2 = unpack_bf2(hs.z), t3 = unpack_bf2(hs.w);
        acc[0] = wself * t0.x; acc[1] = wself * t0.y;
        acc[2] = wself * t1.x; acc[3] = wself * t1.y;
        acc[4] = wself * t2.x; acc[5] = wself * t2.y;
        acc[6] = wself * t3.x; acc[7] = wself * t3.y;
    }
    int i0 = row_ptr[n];
    int cnt = row_ptr[n + 1] - i0;
    if (cnt > 0) {
        int last = cnt - 1;
        int nit = (cnt + 3) >> 2;
        int j0 = g;      float mkA = 1.f; if (j0 > last) { j0 = last; mkA = 0.f; }
        int j1 = 4 + g;  float mkB = 1.f; if (j1 > last) { j1 = last; mkB = 0.f; }
        int j2 = 8 + g;  float mkC = 1.f; if (j2 > last) { j2 = last; mkC = 0.f; }
        int j3 = 12 + g; float mkD = 1.f; if (j3 > last) { j3 = last; mkD = 0.f; }
        uint4 meA = wmp[i0 + j0]; float2 eaA = ea2[i0 + j0];
        uint4 meB = wmp[i0 + j1]; float2 eaB = ea2[i0 + j1];
        uint4 meC = wmp[i0 + j2]; float2 eaC = ea2[i0 + j2];
        uint4 meD = wmp[i0 + j3]; float2 eaD = ea2[i0 + j3];
        float2 alA = *(const float2*)(al_s + 2 * (size_t)meA.x);
        uint4 gvA = h2u4[(size_t)meA.x * 16 + c16];
        float2 alB = *(const float2*)(al_s + 2 * (size_t)meB.x);
        uint4 gvB = h2u4[(size_t)meB.x * 16 + c16];
        float2 alC = *(const float2*)(al_s + 2 * (size_t)meC.x);
        uint4 gvC = h2u4[(size_t)meC.x * 16 + c16];
        for (int it = 0; it < nit - 1; ++it) {
            float2 alD = *(const float2*)(al_s + 2 * (size_t)meD.x);
            uint4 gvD = h2u4[(size_t)meD.x * 16 + c16];
            int jn = 4 * (it + 4) + g;
            float mn = 1.f;
            if (jn > last) { jn = last; mn = 0.f; }
            uint4 meE = wmp[i0 + jn]; float2 eaE = ea2[i0 + jn];
            float lg = (hi ? alA.y : alA.x) + adh + eaA.x * c2x + eaA.y * c2y;
            float wg = __expf(lrelu(lg)) * mkA;
            dsum += wg;
            float2 u;
            u = unpack_bf2(gvA.x); acc[0] = fmaf(wg, u.x, acc[0]); acc[1] = fmaf(wg, u.y, acc[1]);
            u = unpack_bf2(gvA.y); acc[2] = fmaf(wg, u.x, acc[2]); acc[3] = fmaf(wg, u.y, acc[3]);
            u = unpack_bf2(gvA.z); acc[4] = fmaf(wg, u.x, acc[4]); acc[5] = fmaf(wg, u.y, acc[5]);
            u = unpack_bf2(gvA.w); acc[6] = fmaf(wg, u.x, acc[6]); acc[7] = fmaf(wg, u.y, acc[7]);
            meA = meB; meB = meC; meC = meD; meD = meE;
            eaA = eaB; eaB = eaC; eaC = eaD; eaD = eaE;
            alA = alB; alB = alC; alC = alD;
            gvA = gvB; gvB = gvC; gvC = gvD;
            mkA = mkB; mkB = mkC; mkC = mkD; mkD = mn;
        }
        float lg = (hi ? alA.y : alA.x) + adh + eaA.x * c2x + eaA.y * c2y;
        float wg = __expf(lrelu(lg)) * mkA;
        dsum += wg;
        float2 u;
        u = unpack_bf2(gvA.x); acc[0] = fmaf(wg, u.x, acc[0]); acc[1] = fmaf(wg, u.y, acc[1]);
        u = unpack_bf2(gvA.y); acc[2] = fmaf(wg, u.x, acc[2]); acc[3] = fmaf(wg, u.y, acc[3]);
        u = unpack_bf2(gvA.z); acc[4] = fmaf(wg, u.x, acc[4]); acc[5] = fmaf(wg, u.y, acc[5]);
        u = unpack_bf2(gvA.w); acc[6] = fmaf(wg, u.x, acc[6]); acc[7] = fmaf(wg, u.y, acc[7]);
    }
#pragma unroll
    for (int k = 0; k < 8; ++k) {
        acc[k] += __shfl_xor(acc[k], 16);
        acc[k] += __shfl_xor(acc[k], 32);
    }
    dsum += __shfl_xor(dsum, 16);
    dsum += __shfl_xor(dsum, 32);
    if (g == 0) {
        float inv = 1.f / dsum;
        const float* bp = bias + c16 * 8;
        float4 b0 = *(const float4*)bp;
        float4 b1 = *(const float4*)(bp + 4);
        uint4 o;
        o.x = pack_bf2(fmaf(acc[0], inv, b0.x), fmaf(acc[1], inv, b0.y));
        o.y = pack_bf2(fmaf(acc[2], inv, b0.z), fmaf(acc[3], inv, b0.w));
        o.z = pack_bf2(fmaf(acc[4], inv, b1.x), fmaf(acc[5], inv, b1.y));
        o.w = pack_bf2(fmaf(acc[6], inv, b1.z), fmaf(acc[7], inv, b1.w));
        ((uint4*)out)[(size_t)n * 16 + c16] = o;
    }
}

// ---------------- GraphNorm column stats (layer-2 output only) ----------------
template <int C4>
__global__ __launch_bounds__(256) void k_stats_bf(const ushort* __restrict__ x,
                                                  float* __restrict__ stats, int rows) {
    const int C = C4 * 8;
    const int RG = 256 / C4;
    int t = threadIdx.x;
    int c = t & (C4 - 1);
    int rg = t / C4;
    int rpb = (rows + gridDim.x - 1) / gridDim.x;
    int r0 = blockIdx.x * rpb;
    int r1 = r0 + rpb;
    if (r1 > rows) r1 = rows;
    const uint4* xu = (const uint4*)x;
    float s[8] = {0.f, 0.f, 0.f, 0.f, 0.f, 0.f, 0.f, 0.f};
    float q[8] = {0.f, 0.f, 0.f, 0.f, 0.f, 0.f, 0.f, 0.f};
    for (int r = r0 + rg; r < r1; r += RG) {
        uint4 v = xu[(size_t)r * C4 + c];
        float2 a0 = unpack_bf2(v.x), a1 = unpack_bf2(v.y);
        float2 a2 = unpack_bf2(v.z), a3 = unpack_bf2(v.w);
        s[0] += a0.x; q[0] = fmaf(a0.x, a0.x, q[0]);
        s[1] += a0.y; q[1] = fmaf(a0.y, a0.y, q[1]);
        s[2] += a1.x; q[2] = fmaf(a1.x, a1.x, q[2]);
        s[3] += a1.y; q[3] = fmaf(a1.y, a1.y, q[3]);
        s[4] += a2.x; q[4] = fmaf(a2.x, a2.x, q[4]);
        s[5] += a2.y; q[5] = fmaf(a2.y, a2.y, q[5]);
        s[6] += a3.x; q[6] = fmaf(a3.x, a3.x, q[6]);
        s[7] += a3.y; q[7] = fmaf(a3.y, a3.y, q[7]);
    }
    __shared__ float ls[256 * 16];
#pragma unroll
    for (int k = 0; k < 8; ++k) {
        ls[t * 16 + k] = s[k];
        ls[t * 16 + 8 + k] = q[k];
    }
    __syncthreads();
    if (t < C) {
        int cc = t >> 3, k = t & 7;
        float ssum = 0.f, qsum = 0.f;
#pragma unroll
        for (int g = 0; g < RG; ++g) {
            ssum += ls[(g * C4 + cc) * 16 + k];
            qsum += ls[(g * C4 + cc) * 16 + 8 + k];
        }
        atomicAdd(&stats[t], ssum);
        atomicAdd(&stats[C + t], qsum);
    }
}

// ---------------- classifier: per-block coef from stats + fused GraphNorm+ELU ----------------
__global__ __launch_bounds__(256) void k_cls(const ushort* __restrict__ X,
                                             const float* __restrict__ stats,
                                             const float* __restrict__ gw,
                                             const float* __restrict__ gb,
                                             const float* __restrict__ gms,
                                             const float* __restrict__ Wc,
                                             const float* __restrict__ bc,
                                             float* __restrict__ out, int Nn) {
    __shared__ __align__(16) float ls[16 * 132];
    __shared__ __align__(16) float wT[13 * 132];
    __shared__ __align__(16) float ABs[256];
    __shared__ float bS[13];
    int t = threadIdx.x;
    int n0 = blockIdx.x * 16;
    if (t < 128) {
        float inv = 1.f / (float)Nn;
        float mean = stats[t] * inv;
        float cm = mean * gms[t];
        float var = stats[128 + t] * inv - 2.f * cm * mean + cm * cm;
        float A = gw[t] * rsqrtf(var + GEPS);
        ABs[t] = A;
        ABs[128 + t] = gb[t] - A * cm;
    }
    for (int i = t; i < 128 * 13; i += 256) {
        int k = i / 13, j = i - k * 13;
        wT[j * 132 + k] = Wc[i];
    }
    if (t < 13) bS[t] = bc[t];
    __syncthreads();
    const unsigned int* xu = (const unsigned int*)X;
    for (int idx = t; idx < 16 * 64; idx += 256) {
        int r = idx >> 6, ku = idx & 63;
        int row = n0 + r;
        float vx = 0.f, vy = 0.f;
        if (row < Nn) {
            float2 v = unpack_bf2(xu[(size_t)row * 64 + ku]);
            int k = 2 * ku;
            vx = elu_fast(fmaf(ABs[k], v.x, ABs[128 + k]));
            vy = elu_fast(fmaf(ABs[k + 1], v.y, ABs[128 + k + 1]));
        }
        ls[r * 132 + 2 * ku] = vx;
        ls[r * 132 + 2 * ku + 1] = vy;
    }
    __syncthreads();
    if (t < 208) {
        int r = t / 13, j = t - r * 13;
        int row = n0 + r;
        if (row < Nn) {
            float acc = bS[j];
            const float* lr = &ls[r * 132];
            const float* wr = &wT[j * 132];
#pragma unroll 8
            for (int k = 0; k < 128; k += 4) {
                float4 a = *(const float4*)&lr[k];
                float4 b = *(const float4*)&wr[k];
                acc = fmaf(a.x, b.x, fmaf(a.y, b.y, fmaf(a.z, b.z, fmaf(a.w, b.w, acc))));
            }
            out[(size_t)row * 13 + j] = acc;
        }
    }
}

extern "C" void kernel_launch(void* const* d_in, const int* in_sizes, int n_in, void* d_out,
                              int out_size, void* d_ws, size_t ws_size, hipStream_t stream) {
    const float* x = (const float*)d_in[0];
    const int* edge_index = (const int*)d_in[1];
    const float* edge_attr = (const float*)d_in[2];
    const float* W1 = (const float*)d_in[3];
    const float* We1 = (const float*)d_in[4];
    const float* as1 = (const float*)d_in[5];
    const float* ad1 = (const float*)d_in[6];
    const float* ae1 = (const float*)d_in[7];
    const float* b1 = (const float*)d_in[8];
    const float* gn1_w = (const float*)d_in[9];
    const float* gn1_b = (const float*)d_in[10];
    const float* gn1_ms = (const float*)d_in[11];
    const float* W2 = (const float*)d_in[12];
    const float* We2 = (const float*)d_in[13];
    const float* as2 = (const float*)d_in[14];
    const float* ad2 = (const float*)d_in[15];
    const float* ae2 = (const float*)d_in[16];
    const float* b2 = (const float*)d_in[17];
    const float* gn2_w = (const float*)d_in[18];
    const float* gn2_b = (const float*)d_in[19];
    const float* gn2_ms = (const float*)d_in[20];
    const float* Wc = (const float*)d_in[21];
    const float* bc = (const float*)d_in[22];

    const int N = in_sizes[0] / 3;
    const int E = in_sizes[1] / 2;
    const int* srcv = edge_index;
    const int* dstv = edge_index + E;

    // ---- workspace carve (256B-aligned, byte-based) ----
    char* w = (char*)d_ws;
    auto carveB = [&](size_t bytes) -> void* {
        void* p = (void*)w;
        w += ((bytes + 255) / 256) * 256;
        return p;
    };
    // zeroed region first:
    int* deg = (int*)carveB((size_t)N * 4);
    float* ea_sum = (float*)carveB(8);
    float* mom = (float*)carveB(36 * 4);
    float* statsB = (float*)carveB(256 * 4);
    char* zero_end = w;
    // not zeroed:
    int* row_ptr = (int*)carveB((size_t)(N + 1) * 4);
    int* bsum = (int*)carveB(1024 * 4);
    float2* ea2 = (float2*)carveB((size_t)E * 8);
    uint4* wmp = (uint4*)carveB((size_t)E * 16);
    float* C1 = (float*)carveB(8 * 4);
    float* C2 = (float*)carveB(4 * 4);
    float* Ps = (float*)carveB(12 * 4);
    float* Pd = (float*)carveB(12 * 4);
    float* lE1 = (float*)carveB(4 * 4);
    float* lE2 = (float*)carveB(2 * 4);
    uint4* Bfrag = (uint4*)carveB(4096 * 16);
    float* al_s1 = (float*)carveB((size_t)N * 4 * 4);
    float* al_d1 = (float*)carveB((size_t)N * 4 * 4);
    float* al_s2 = (float*)carveB((size_t)N * 2 * 4);
    float* al_d2 = (float*)carveB((size_t)N * 2 * 4);
    float4* uarr = (float4*)carveB((size_t)N * 4 * 16);   // per-node per-head u (48B + pad)
    ushort* h2b = (ushort*)carveB((size_t)N * 128 * 2);   // bf16 h2
    ushort* out2b = (ushort*)carveB((size_t)N * 128 * 2); // bf16 layer-2 output

    hipMemsetAsync(deg, 0, (size_t)(zero_end - (char*)deg), stream);

    const int nb1 = (N + 1023) / 1024;
    const int ebl = (E + 255) / 256;

    k_pre<<<17 + 256, 256, 0, stream>>>(W1, as1, ad1, edge_attr, dstv, W2, We1, ae1, We2, ae2,
                                        ea_sum, deg, Bfrag, C1, C2, Ps, Pd, E);
    k_scan1<<<nb1, 1024, 0, stream>>>(deg, row_ptr, bsum, N);
    k_scan23<<<nb1, 1024, 0, stream>>>(row_ptr, bsum, ea_sum, C1, C2, Ps, Pd, x, al_s1, al_d1,
                                       lE1, lE2, N, E);
    k_scatfill<<<ebl, 256, 0, stream>>>(dstv, srcv, edge_attr, row_ptr, deg, al_s1, al_d1, C1,
                                        ea2, wmp, E);
    k_agg1<<<(N + 7) / 8, 256, 0, stream>>>(x, row_ptr, wmp, al_s1, al_d1, lE1, uarr, N);
    k_mom<<<128, 256, 0, stream>>>(uarr, mom, N * 4);
    k_gemm2_mfma<<<(N + 63) / 64, 256, 0, stream>>>(uarr, mom, W1, b1, gn1_w, gn1_b, gn1_ms,
                                                    Bfrag, as2, ad2, h2b, al_s2, al_d2, N);
    k_agg2<<<(N + 3) / 4, 256, 0, stream>>>(h2b, row_ptr, wmp, ea2, al_s2, al_d2, C2, lE2, b2,
                                            out2b, N);
    k_stats_bf<16><<<256, 256, 0, stream>>>(out2b, statsB, N);
    k_cls<<<(N + 15) / 16, 256, 0, stream>>>(out2b, statsB, gn2_w, gn2_b, gn2_ms, Wc, bc,
                                             (float*)d_out, N);
}